// Round 1
// baseline (2356.014 us; speedup 1.0000x reference)
//
#include <hip/hip_runtime.h>
#include <math.h>

#define N_   4
#define C_   128
#define H_   128
#define W_   128
#define HW_  16384
#define C2_  64
#define HD_  32
#define SCALE_ 0.17677669529663687f   // 32^-0.5

// ---------------------------------------------------------------------------
// Kernel 1: LayerNorm over C=128 + Q projection (q = ln(x) @ q_w.T + q_b)
// input inp is (N, C, H*W); q out is (N, HW, 128)
// block = 256 threads handles 64 consecutive tokens of one image
// ---------------------------------------------------------------------------
__global__ __launch_bounds__(256) void ln_q_kernel(
    const float* __restrict__ inp, const float* __restrict__ nw,
    const float* __restrict__ nb, const float* __restrict__ qw,
    const float* __restrict__ qb, float* __restrict__ q) {
  __shared__ float xs[128 * 64];
  __shared__ float mu[64], rs[64];
  int bid = blockIdx.x;            // 1024 blocks (4 n * 256 tiles)
  int n  = bid >> 8;
  int t0 = (bid & 255) * 64;
  const float* xb = inp + (size_t)n * C_ * HW_;
  for (int idx = threadIdx.x; idx < 128 * 64; idx += 256) {
    int c = idx >> 6, tt = idx & 63;
    xs[idx] = xb[c * HW_ + t0 + tt];        // coalesced in tt
  }
  __syncthreads();
  if (threadIdx.x < 64) {
    int tt = threadIdx.x;
    float s = 0.f;
    for (int c = 0; c < 128; ++c) s += xs[c * 64 + tt];
    float m = s * (1.0f / 128.0f);
    float v = 0.f;
    for (int c = 0; c < 128; ++c) { float d = xs[c * 64 + tt] - m; v += d * d; }
    v *= (1.0f / 128.0f);
    mu[tt] = m;
    rs[tt] = rsqrtf(v + 1e-5f);
  }
  __syncthreads();
  for (int idx = threadIdx.x; idx < 128 * 64; idx += 256) {
    int c = idx >> 6, tt = idx & 63;
    xs[idx] = (xs[idx] - mu[tt]) * rs[tt] * nw[c] + nb[c];
  }
  __syncthreads();
  for (int idx = threadIdx.x; idx < 64 * 128; idx += 256) {
    int tt = idx >> 7, o = idx & 127;
    float s = qb[o];
    const float* wrow = qw + o * 128;
    #pragma unroll 8
    for (int c = 0; c < 128; ++c) s += xs[c * 64 + tt] * wrow[c];  // xs broadcast
    q[((size_t)n * HW_ + t0 + tt) * 128 + o] = s;                  // coalesced in o
  }
}

// ---------------------------------------------------------------------------
// Kernel 2: patch-embed conv (stride == kernel == P), windowed with NW x NW.
// y[token, c2] = sum_{ci,kh,kw} inp_patch * w[c2,ci,kh,kw] + b[c2]
// block = 256 threads per output token; patch staged in LDS.
// ---------------------------------------------------------------------------
template <int P, int NW>
__global__ __launch_bounds__(256) void conv_kernel(
    const float* __restrict__ inp, const float* __restrict__ w,
    const float* __restrict__ b, float* __restrict__ y, int head_off) {
  constexpr int PT   = 128 * P * P;   // floats per patch
  constexpr int HWIN = H_ / NW;       // window spatial size
  constexpr int G    = HWIN / P;      // conv out grid per window
  constexpr int L    = G * G;         // tokens per window
  __shared__ float patch[PT];
  __shared__ float partial[4][64];
  int bid  = blockIdx.x;              // B * L
  int bwin = bid / L, loc = bid % L;
  int n  = bwin / (NW * NW);
  int wy = (bwin / NW) % NW, wx = bwin % NW;
  int oh = loc / G, ow = loc % G;
  int r0 = wy * HWIN + oh * P, c0 = wx * HWIN + ow * P;
  const float* xb = inp + (size_t)n * C_ * HW_;
  for (int idx = threadIdx.x; idx < PT; idx += 256) {
    int ci  = idx / (P * P);
    int rem = idx % (P * P);
    int kh = rem / P, kw = rem % P;
    patch[idx] = xb[ci * HW_ + (r0 + kh) * W_ + c0 + kw];
  }
  __syncthreads();
  int part = threadIdx.x >> 6, c2 = threadIdx.x & 63;
  constexpr int KQ = PT / 4;
  const float* wr = w + (size_t)c2 * PT + part * KQ;
  const float* pr = patch + part * KQ;
  float s = 0.f;
  #pragma unroll 8
  for (int k = 0; k < KQ; ++k) s += pr[k] * wr[k];
  partial[part][c2] = s;
  __syncthreads();
  if (threadIdx.x < 64) {
    float t = partial[0][threadIdx.x] + partial[1][threadIdx.x] +
              partial[2][threadIdx.x] + partial[3][threadIdx.x] + b[threadIdx.x];
    y[(size_t)(head_off + bid) * 64 + threadIdx.x] = t;
  }
}

// ---------------------------------------------------------------------------
// Kernel 3: per-token LN(64) + exact GELU + KV projection (64 -> 32 k + 32 v)
// one wave per token, 4 tokens per block.
// ---------------------------------------------------------------------------
__global__ __launch_bounds__(256) void lnkv_kernel(
    const float* __restrict__ y, const float* __restrict__ lnw,
    const float* __restrict__ lnb, const float* __restrict__ kvw,
    const float* __restrict__ kvb, float* __restrict__ kbuf,
    float* __restrict__ vbuf, int head_off) {
  __shared__ float xg[4][64];
  int wv = threadIdx.x >> 6, lane = threadIdx.x & 63;
  int token = blockIdx.x * 4 + wv;   // grids sized exactly (ntok % 4 == 0)
  float x = y[(size_t)(head_off + token) * 64 + lane];
  float s = x;
  for (int m = 1; m < 64; m <<= 1) s += __shfl_xor(s, m, 64);
  float mean = s * (1.0f / 64.0f);
  float d = x - mean;
  float v = d * d;
  for (int m = 1; m < 64; m <<= 1) v += __shfl_xor(v, m, 64);
  v *= (1.0f / 64.0f);
  float xn = d * rsqrtf(v + 1e-5f) * lnw[lane] + lnb[lane];
  float g  = 0.5f * xn * (1.0f + erff(xn * 0.70710678118654752f));
  xg[wv][lane] = g;
  __syncthreads();
  float acc = kvb[lane];
  const float* wr = kvw + lane * 64;
  #pragma unroll 8
  for (int c = 0; c < 64; ++c) acc += xg[wv][c] * wr[c];
  if (lane < 32) kbuf[(size_t)(head_off + token) * 32 + lane] = acc;
  else           vbuf[(size_t)(head_off + token) * 32 + (lane - 32)] = acc;
}

// ---------------------------------------------------------------------------
// Kernel 4: attention for one head. Thread-per-query online softmax,
// K/V staged in LDS. Writes head output into cbuf (N, HW, 128) at head*32.
// ---------------------------------------------------------------------------
template <int NW, int LK>
__global__ __launch_bounds__(256) void attn_kernel(
    const float* __restrict__ q, const float* __restrict__ kbuf,
    const float* __restrict__ vbuf, float* __restrict__ cbuf,
    int head, int head_off) {
  constexpr int HWIN  = H_ / NW;
  constexpr int LQ    = HWIN * HWIN;
  constexpr int TILES = LQ / 256;
  __shared__ float kl[LK * 32];
  __shared__ float vl[LK * 32];
  int bid  = blockIdx.x;
  int bwin = bid / TILES, tile = bid % TILES;
  int n  = bwin / (NW * NW);
  int wy = (bwin / NW) % NW, wx = bwin % NW;
  const float* kb = kbuf + (size_t)(head_off + bwin * LK) * 32;
  const float* vb = vbuf + (size_t)(head_off + bwin * LK) * 32;
  for (int idx = threadIdx.x; idx < LK * 32; idx += 256) {
    kl[idx] = kb[idx];
    vl[idx] = vb[idx];
  }
  __syncthreads();
  int j  = tile * 256 + threadIdx.x;
  int ih = j / HWIN, iw = j % HWIN;
  int t  = (wy * HWIN + ih) * W_ + wx * HWIN + iw;
  const float* qp = q + ((size_t)n * HW_ + t) * 128 + head * 32;
  float qr[32];
  #pragma unroll
  for (int d2 = 0; d2 < 32; ++d2) qr[d2] = qp[d2];
  float m = -1e30f, l = 0.f;
  float acc[32];
  #pragma unroll
  for (int d2 = 0; d2 < 32; ++d2) acc[d2] = 0.f;
  for (int kk = 0; kk < LK; ++kk) {
    const float* kr = kl + kk * 32;
    float s = 0.f;
    #pragma unroll
    for (int d2 = 0; d2 < 32; ++d2) s += qr[d2] * kr[d2];
    s *= SCALE_;
    float mn   = fmaxf(m, s);
    float corr = __expf(m - mn);
    float e    = __expf(s - mn);
    l = l * corr + e;
    const float* vr = vl + kk * 32;
    #pragma unroll
    for (int d2 = 0; d2 < 32; ++d2) acc[d2] = acc[d2] * corr + e * vr[d2];
    m = mn;
  }
  float inv = 1.0f / l;
  float* op = cbuf + ((size_t)n * HW_ + t) * 128 + head * 32;
  #pragma unroll
  for (int d2 = 0; d2 < 32; ++d2) op[d2] = acc[d2] * inv;
}

// ---------------------------------------------------------------------------
// Kernel 5: final projection, IN PLACE on the concat buffer (= d_out).
// Each block stages its 64 rows in LDS (sync), then overwrites them.
// ---------------------------------------------------------------------------
__global__ __launch_bounds__(256) void proj_kernel(
    float* __restrict__ cbuf, const float* __restrict__ pw,
    const float* __restrict__ pb, float* __restrict__ out) {
  __shared__ float xs[64 * 128];
  size_t r0 = (size_t)blockIdx.x * 64;
  for (int idx = threadIdx.x; idx < 64 * 128; idx += 256)
    xs[idx] = cbuf[r0 * 128 + idx];
  __syncthreads();
  for (int idx = threadIdx.x; idx < 64 * 128; idx += 256) {
    int rr = idx >> 7, o = idx & 127;
    float s = pb[o];
    const float* wr = pw + o * 128;
    const float* xr = xs + rr * 128;
    #pragma unroll 8
    for (int c = 0; c < 128; ++c) s += xr[c] * wr[c];
    out[(r0 + rr) * 128 + o] = s;
  }
}

// ---------------------------------------------------------------------------
extern "C" void kernel_launch(void* const* d_in, const int* in_sizes, int n_in,
                              void* d_out, int out_size, void* d_ws, size_t ws_size,
                              hipStream_t stream) {
  const float* inp = (const float*)d_in[0];
  const float* nw  = (const float*)d_in[1];
  const float* nb  = (const float*)d_in[2];
  const float* qw  = (const float*)d_in[3];
  const float* qb  = (const float*)d_in[4];
  const float* pw  = (const float*)d_in[29];
  const float* pb  = (const float*)d_in[30];

  float* ws   = (float*)d_ws;
  float* q    = ws;                    //  8,388,608 floats
  float* y    = q + 8388608;           //  1,638,400
  float* kbuf = y + 1638400;           //    819,200
  float* vbuf = kbuf + 819200;         //    819,200
  float* cbuf = (float*)d_out;         // concat buffer == output (proj in place)

  // 1) LN + Q projection
  ln_q_kernel<<<1024, 256, 0, stream>>>(inp, nw, nb, qw, qb, q);

  // 2) patch-embed convs (head token offsets 0 / 1024 / 5120 / 9216)
  conv_kernel<8, 1><<<1024,  256, 0, stream>>>(inp, (const float*)d_in[5],  (const float*)d_in[6],  y, 0);
  conv_kernel<4, 2><<<4096,  256, 0, stream>>>(inp, (const float*)d_in[11], (const float*)d_in[12], y, 1024);
  conv_kernel<4, 4><<<4096,  256, 0, stream>>>(inp, (const float*)d_in[17], (const float*)d_in[18], y, 5120);
  conv_kernel<2, 8><<<16384, 256, 0, stream>>>(inp, (const float*)d_in[23], (const float*)d_in[24], y, 9216);

  // 3) LN + GELU + KV projection per head
  lnkv_kernel<<<256,  256, 0, stream>>>(y, (const float*)d_in[7],  (const float*)d_in[8],  (const float*)d_in[9],  (const float*)d_in[10], kbuf, vbuf, 0);
  lnkv_kernel<<<1024, 256, 0, stream>>>(y, (const float*)d_in[13], (const float*)d_in[14], (const float*)d_in[15], (const float*)d_in[16], kbuf, vbuf, 1024);
  lnkv_kernel<<<1024, 256, 0, stream>>>(y, (const float*)d_in[19], (const float*)d_in[20], (const float*)d_in[21], (const float*)d_in[22], kbuf, vbuf, 5120);
  lnkv_kernel<<<4096, 256, 0, stream>>>(y, (const float*)d_in[25], (const float*)d_in[26], (const float*)d_in[27], (const float*)d_in[28], kbuf, vbuf, 9216);

  // 4) attention per head -> writes concat channels head*32..head*32+31
  attn_kernel<1, 256><<<256, 256, 0, stream>>>(q, kbuf, vbuf, cbuf, 0, 0);
  attn_kernel<2, 256><<<256, 256, 0, stream>>>(q, kbuf, vbuf, cbuf, 1, 1024);
  attn_kernel<4, 64><<<256, 256, 0, stream>>>(q, kbuf, vbuf, cbuf, 2, 5120);
  attn_kernel<8, 64><<<256, 256, 0, stream>>>(q, kbuf, vbuf, cbuf, 3, 9216);

  // 5) final projection, in place on d_out
  proj_kernel<<<1024, 256, 0, stream>>>(cbuf, pw, pb, (float*)d_out);
}

// Round 2
// 540.091 us; speedup vs baseline: 4.3623x; 4.3623x over previous
//
#include <hip/hip_runtime.h>
#include <math.h>

#define N_   4
#define C_   128
#define H_   128
#define W_   128
#define HW_  16384
#define SCALE_ 0.17677669529663687f   // 32^-0.5

// ws float offsets
#define Y_OFF    0           // 1,638,400 floats (aliases xn region, used after q-GEMM)
#define K_OFF    1638400     //   819,200
#define V_OFF    2457600     //   819,200
#define PART_OFF 3276800     // 1,048,576
#define XN_OFF   0           // 8,388,608 (dead after q-GEMM)
#define Q_OFF    8388608     // 8,388,608
// total ws: 16,777,216 floats = 64 MB

// ---------------------------------------------------------------------------
// LayerNorm over C=128 -> xn (65536 x 128)
// ---------------------------------------------------------------------------
__global__ __launch_bounds__(256) void ln_kernel(
    const float* __restrict__ inp, const float* __restrict__ nw,
    const float* __restrict__ nb, float* __restrict__ xn) {
  __shared__ float xs[128 * 65];
  __shared__ float ps[4][64], ps2[4][64];
  __shared__ float mu[64], rs[64];
  int bid = blockIdx.x;            // 1024
  int n  = bid >> 8;
  int t0 = (bid & 255) * 64;
  const float* xb = inp + (size_t)n * C_ * HW_;
  for (int idx = threadIdx.x; idx < 128 * 64; idx += 256) {
    int c = idx >> 6, tt = idx & 63;
    xs[c * 65 + tt] = xb[c * HW_ + t0 + tt];     // coalesced
  }
  __syncthreads();
  {
    int tt = threadIdx.x & 63, part = threadIdx.x >> 6;
    float s = 0.f, s2 = 0.f;
    for (int c = part * 32; c < part * 32 + 32; ++c) {
      float v = xs[c * 65 + tt];
      s += v; s2 += v * v;
    }
    ps[part][tt] = s; ps2[part][tt] = s2;
  }
  __syncthreads();
  if (threadIdx.x < 64) {
    int tt = threadIdx.x;
    float s  = ps[0][tt] + ps[1][tt] + ps[2][tt] + ps[3][tt];
    float s2 = ps2[0][tt] + ps2[1][tt] + ps2[2][tt] + ps2[3][tt];
    float m = s * (1.0f / 128.0f);
    float v = s2 * (1.0f / 128.0f) - m * m;
    mu[tt] = m;
    rs[tt] = rsqrtf(v + 1e-5f);
  }
  __syncthreads();
  for (int idx = threadIdx.x; idx < 64 * 128; idx += 256) {
    int c = idx & 127, tt = idx >> 7;
    xn[((size_t)bid * 64 + tt) * 128 + c] =
        (xs[c * 65 + tt] - mu[tt]) * rs[tt] * nw[c] + nb[c];
  }
}

// ---------------------------------------------------------------------------
// Tiled fp32 GEMM: out[r][o] = x[r][0:128] . w[o][0:128] + b[o], NO=128
// 64-row tile per block, 256 threads, 8x4 accs/thread. In-place safe.
// ---------------------------------------------------------------------------
__global__ __launch_bounds__(256) void gemm128_kernel(
    const float* __restrict__ x, const float* __restrict__ w,
    const float* __restrict__ b, float* __restrict__ out) {
  __shared__ float xs[64 * 36];
  __shared__ float ws[128 * 36];
  int r0 = blockIdx.x * 64;
  int tx = threadIdx.x & 31, ty = threadIdx.x >> 5;
  float acc[8][4] = {};
  for (int k0 = 0; k0 < 128; k0 += 32) {
    #pragma unroll
    for (int it = 0; it < 2; ++it) {
      int idx = threadIdx.x + it * 256;
      int row = idx >> 3, kq = idx & 7;
      *(float4*)&xs[row * 36 + kq * 4] =
          *(const float4*)&x[(size_t)(r0 + row) * 128 + k0 + kq * 4];
    }
    #pragma unroll
    for (int it = 0; it < 4; ++it) {
      int idx = threadIdx.x + it * 256;
      int o = idx >> 3, kq = idx & 7;
      *(float4*)&ws[o * 36 + kq * 4] =
          *(const float4*)&w[(size_t)o * 128 + k0 + kq * 4];
    }
    __syncthreads();
    #pragma unroll
    for (int k4 = 0; k4 < 8; ++k4) {
      float4 xv[8], wv[4];
      #pragma unroll
      for (int i = 0; i < 8; ++i) xv[i] = *(const float4*)&xs[(ty * 8 + i) * 36 + k4 * 4];
      #pragma unroll
      for (int j = 0; j < 4; ++j) wv[j] = *(const float4*)&ws[(tx + 32 * j) * 36 + k4 * 4];
      #pragma unroll
      for (int i = 0; i < 8; ++i)
        #pragma unroll
        for (int j = 0; j < 4; ++j)
          acc[i][j] += xv[i].x * wv[j].x + xv[i].y * wv[j].y +
                       xv[i].z * wv[j].z + xv[i].w * wv[j].w;
    }
    __syncthreads();
  }
  #pragma unroll
  for (int i = 0; i < 8; ++i) {
    size_t row = r0 + ty * 8 + i;
    #pragma unroll
    for (int j = 0; j < 4; ++j) {
      int o = tx + 32 * j;
      out[row * 128 + o] = acc[i][j] + b[o];
    }
  }
}

// ---------------------------------------------------------------------------
// Conv-as-GEMM with fused im2col gather. BM=64 tokens, BN=64 outs, BK=32.
// SEG>1: writes K-split partials (no bias). SEG==1: writes y directly.
// ---------------------------------------------------------------------------
template <int P, int NW, int SEG>
__global__ __launch_bounds__(256) void conv_gemm_kernel(
    const float* __restrict__ inp, const float* __restrict__ w,
    const float* __restrict__ b, float* __restrict__ dst, int head_off) {
  constexpr int K    = 128 * P * P;
  constexpr int KSEG = K / SEG;
  constexpr int HWIN = H_ / NW;
  constexpr int G    = HWIN / P;
  constexpr int L    = G * G;
  constexpr int M    = 4 * NW * NW * L;
  constexpr int LGL  = (L == 256) ? 8 : 6;
  constexpr int LGG  = (G == 16) ? 4 : 3;
  constexpr int LGNW = (NW == 8) ? 3 : (NW == 4) ? 2 : (NW == 2) ? 1 : 0;
  constexpr int LGP  = (P == 8) ? 3 : (P == 4) ? 2 : 1;
  constexpr int LGP2 = 2 * LGP;
  __shared__ float xs[64 * 36];
  __shared__ float ws[64 * 36];
  int t0 = blockIdx.x * 64;
  int kbase = blockIdx.y * KSEG;
  int tx = threadIdx.x & 31, ty = threadIdx.x >> 5;
  float acc[8][2] = {};
  for (int k0 = kbase; k0 < kbase + KSEG; k0 += 32) {
    #pragma unroll
    for (int it = 0; it < 2; ++it) {
      int idx = threadIdx.x + it * 256;
      int o = idx >> 3, kq = idx & 7;
      *(float4*)&ws[o * 36 + kq * 4] =
          *(const float4*)&w[(size_t)o * K + k0 + kq * 4];
    }
    #pragma unroll
    for (int it = 0; it < 2; ++it) {
      int idx = threadIdx.x + it * 256;
      int row = idx >> 3, kq = idx & 7;
      int tglob = t0 + row;
      int bwin = tglob >> LGL;
      int loc  = tglob & (L - 1);
      int n    = bwin >> (2 * LGNW);
      int wrem = bwin & (NW * NW - 1);
      int wy = wrem >> LGNW, wx = wrem & (NW - 1);
      int oh = loc >> LGG,   ow = loc & (G - 1);
      int k  = k0 + kq * 4;
      int ci = k >> LGP2;
      int wp = k & (P * P - 1);
      int kh = wp >> LGP, kwp = wp & (P - 1);
      int rr = wy * HWIN + oh * P + kh;
      int cc = wx * HWIN + ow * P + kwp;
      const float* src = inp + ((size_t)n * C_ + ci) * HW_ + rr * W_ + cc;
      if constexpr (P >= 4) {
        *(float4*)&xs[row * 36 + kq * 4] = *(const float4*)src;
      } else {
        float2 a  = *(const float2*)src;
        float2 bb = *(const float2*)(src + W_);
        *(float4*)&xs[row * 36 + kq * 4] = make_float4(a.x, a.y, bb.x, bb.y);
      }
    }
    __syncthreads();
    #pragma unroll
    for (int k4 = 0; k4 < 8; ++k4) {
      float4 xv[8], wv[2];
      #pragma unroll
      for (int i = 0; i < 8; ++i) xv[i] = *(const float4*)&xs[(ty * 8 + i) * 36 + k4 * 4];
      #pragma unroll
      for (int j = 0; j < 2; ++j) wv[j] = *(const float4*)&ws[(tx + 32 * j) * 36 + k4 * 4];
      #pragma unroll
      for (int i = 0; i < 8; ++i)
        #pragma unroll
        for (int j = 0; j < 2; ++j)
          acc[i][j] += xv[i].x * wv[j].x + xv[i].y * wv[j].y +
                       xv[i].z * wv[j].z + xv[i].w * wv[j].w;
    }
    __syncthreads();
  }
  #pragma unroll
  for (int i = 0; i < 8; ++i) {
    int row = t0 + ty * 8 + i;
    #pragma unroll
    for (int j = 0; j < 2; ++j) {
      int o = tx + 32 * j;
      if constexpr (SEG == 1) {
        dst[(size_t)(head_off + row) * 64 + o] = acc[i][j] + b[o];
      } else {
        dst[((size_t)blockIdx.y * M + row) * 64 + o] = acc[i][j];
      }
    }
  }
}

// reduce K-split partials: y[ho+t][o] = b[o] + sum_seg part[seg][t][o]
__global__ __launch_bounds__(256) void reduce_kernel(
    const float* __restrict__ part, const float* __restrict__ b,
    float* __restrict__ y, int M, int SEG, int head_off) {
  int idx = blockIdx.x * 256 + threadIdx.x;
  if (idx >= M * 64) return;
  int o = idx & 63;
  float s = b[o];
  for (int sgi = 0; sgi < SEG; ++sgi) s += part[(size_t)sgi * M * 64 + idx];
  y[(size_t)head_off * 64 + idx] = s;
}

// ---------------------------------------------------------------------------
// per-token LN(64) + exact GELU + KV projection (64 -> 32 k + 32 v)
// ---------------------------------------------------------------------------
__global__ __launch_bounds__(256) void lnkv_kernel(
    const float* __restrict__ y, const float* __restrict__ lnw,
    const float* __restrict__ lnb, const float* __restrict__ kvw,
    const float* __restrict__ kvb, float* __restrict__ kbuf,
    float* __restrict__ vbuf, int head_off) {
  __shared__ float xg[4][64];
  int wv = threadIdx.x >> 6, lane = threadIdx.x & 63;
  int token = blockIdx.x * 4 + wv;
  float x = y[(size_t)(head_off + token) * 64 + lane];
  float s = x;
  for (int m = 1; m < 64; m <<= 1) s += __shfl_xor(s, m, 64);
  float mean = s * (1.0f / 64.0f);
  float d = x - mean;
  float v = d * d;
  for (int m = 1; m < 64; m <<= 1) v += __shfl_xor(v, m, 64);
  v *= (1.0f / 64.0f);
  float xn = d * rsqrtf(v + 1e-5f) * lnw[lane] + lnb[lane];
  float g  = 0.5f * xn * (1.0f + erff(xn * 0.70710678118654752f));
  xg[wv][lane] = g;
  __syncthreads();
  float acc = kvb[lane];
  const float* wr = kvw + lane * 64;
  #pragma unroll 8
  for (int c = 0; c < 64; ++c) acc += xg[wv][c] * wr[c];
  if (lane < 32) kbuf[(size_t)(head_off + token) * 32 + lane] = acc;
  else           vbuf[(size_t)(head_off + token) * 32 + (lane - 32)] = acc;
}

// ---------------------------------------------------------------------------
// attention: thread-per-query online softmax, K/V in LDS
// ---------------------------------------------------------------------------
template <int NW, int LK>
__global__ __launch_bounds__(256) void attn_kernel(
    const float* __restrict__ q, const float* __restrict__ kbuf,
    const float* __restrict__ vbuf, float* __restrict__ cbuf,
    int head, int head_off) {
  constexpr int HWIN  = H_ / NW;
  constexpr int LQ    = HWIN * HWIN;
  constexpr int TILES = LQ / 256;
  __shared__ float kl[LK * 32];
  __shared__ float vl[LK * 32];
  int bid  = blockIdx.x;
  int bwin = bid / TILES, tile = bid % TILES;
  int n  = bwin / (NW * NW);
  int wy = (bwin / NW) % NW, wx = bwin % NW;
  const float* kb = kbuf + (size_t)(head_off + bwin * LK) * 32;
  const float* vb = vbuf + (size_t)(head_off + bwin * LK) * 32;
  for (int idx = threadIdx.x; idx < LK * 32; idx += 256) {
    kl[idx] = kb[idx];
    vl[idx] = vb[idx];
  }
  __syncthreads();
  int j  = tile * 256 + threadIdx.x;
  int ih = j / HWIN, iw = j % HWIN;
  int t  = (wy * HWIN + ih) * W_ + wx * HWIN + iw;
  const float* qp = q + ((size_t)n * HW_ + t) * 128 + head * 32;
  float qr[32];
  #pragma unroll
  for (int d2 = 0; d2 < 32; ++d2) qr[d2] = qp[d2];
  float m = -1e30f, l = 0.f;
  float acc[32];
  #pragma unroll
  for (int d2 = 0; d2 < 32; ++d2) acc[d2] = 0.f;
  for (int kk = 0; kk < LK; ++kk) {
    const float* kr = kl + kk * 32;
    float s = 0.f;
    #pragma unroll
    for (int d2 = 0; d2 < 32; ++d2) s += qr[d2] * kr[d2];
    s *= SCALE_;
    float mn   = fmaxf(m, s);
    float corr = __expf(m - mn);
    float e    = __expf(s - mn);
    l = l * corr + e;
    const float* vr = vl + kk * 32;
    #pragma unroll
    for (int d2 = 0; d2 < 32; ++d2) acc[d2] = acc[d2] * corr + e * vr[d2];
    m = mn;
  }
  float inv = 1.0f / l;
  float* op = cbuf + ((size_t)n * HW_ + t) * 128 + head * 32;
  #pragma unroll
  for (int d2 = 0; d2 < 32; ++d2) op[d2] = acc[d2] * inv;
}

// ---------------------------------------------------------------------------
extern "C" void kernel_launch(void* const* d_in, const int* in_sizes, int n_in,
                              void* d_out, int out_size, void* d_ws, size_t ws_size,
                              hipStream_t stream) {
  const float* inp = (const float*)d_in[0];
  const float* nw  = (const float*)d_in[1];
  const float* nb  = (const float*)d_in[2];
  const float* qw  = (const float*)d_in[3];
  const float* qb  = (const float*)d_in[4];
  const float* pw  = (const float*)d_in[29];
  const float* pb  = (const float*)d_in[30];

  float* ws   = (float*)d_ws;
  float* xn   = ws + XN_OFF;
  float* q    = ws + Q_OFF;
  float* y    = ws + Y_OFF;
  float* kbuf = ws + K_OFF;
  float* vbuf = ws + V_OFF;
  float* part = ws + PART_OFF;
  float* cbuf = (float*)d_out;

  // 1) LN -> xn ; 2) q = xn @ qw.T + qb
  ln_kernel<<<1024, 256, 0, stream>>>(inp, nw, nb, xn);
  gemm128_kernel<<<1024, 256, 0, stream>>>(xn, qw, qb, q);
  // (xn region now dead; y/kbuf/vbuf/part alias it)

  // 3) convs (K-split partials where M is small) + reduce + lnkv, per head
  conv_gemm_kernel<8, 1, 16><<<dim3(16, 16), 256, 0, stream>>>(inp, (const float*)d_in[5],  (const float*)d_in[6],  part, 0);
  reduce_kernel<<<256, 256, 0, stream>>>(part, (const float*)d_in[6], y, 1024, 16, 0);
  lnkv_kernel<<<256, 256, 0, stream>>>(y, (const float*)d_in[7], (const float*)d_in[8], (const float*)d_in[9], (const float*)d_in[10], kbuf, vbuf, 0);

  conv_gemm_kernel<4, 2, 4><<<dim3(64, 4), 256, 0, stream>>>(inp, (const float*)d_in[11], (const float*)d_in[12], part, 0);
  reduce_kernel<<<1024, 256, 0, stream>>>(part, (const float*)d_in[12], y, 4096, 4, 1024);
  lnkv_kernel<<<1024, 256, 0, stream>>>(y, (const float*)d_in[13], (const float*)d_in[14], (const float*)d_in[15], (const float*)d_in[16], kbuf, vbuf, 1024);

  conv_gemm_kernel<4, 4, 4><<<dim3(64, 4), 256, 0, stream>>>(inp, (const float*)d_in[17], (const float*)d_in[18], part, 0);
  reduce_kernel<<<1024, 256, 0, stream>>>(part, (const float*)d_in[18], y, 4096, 4, 5120);
  lnkv_kernel<<<1024, 256, 0, stream>>>(y, (const float*)d_in[19], (const float*)d_in[20], (const float*)d_in[21], (const float*)d_in[22], kbuf, vbuf, 5120);

  conv_gemm_kernel<2, 8, 1><<<dim3(256, 1), 256, 0, stream>>>(inp, (const float*)d_in[23], (const float*)d_in[24], y, 9216);
  lnkv_kernel<<<4096, 256, 0, stream>>>(y, (const float*)d_in[25], (const float*)d_in[26], (const float*)d_in[27], (const float*)d_in[28], kbuf, vbuf, 9216);

  // 4) attention per head -> concat channels in cbuf (= d_out)
  attn_kernel<1, 256><<<256, 256, 0, stream>>>(q, kbuf, vbuf, cbuf, 0, 0);
  attn_kernel<2, 256><<<256, 256, 0, stream>>>(q, kbuf, vbuf, cbuf, 1, 1024);
  attn_kernel<4, 64><<<256, 256, 0, stream>>>(q, kbuf, vbuf, cbuf, 2, 5120);
  attn_kernel<8, 64><<<256, 256, 0, stream>>>(q, kbuf, vbuf, cbuf, 3, 9216);

  // 5) final projection, in place on d_out
  gemm128_kernel<<<1024, 256, 0, stream>>>(cbuf, pw, pb, (float*)d_out);
}

// Round 3
// 462.121 us; speedup vs baseline: 5.0983x; 1.1687x over previous
//
#include <hip/hip_runtime.h>
#include <math.h>

#define N_   4
#define C_   128
#define H_   128
#define W_   128
#define HW_  16384
#define SCALE_ 0.17677669529663687f   // 32^-0.5

typedef unsigned short u16;
typedef __bf16 bf16x8 __attribute__((ext_vector_type(8)));
typedef float  f32x4  __attribute__((ext_vector_type(4)));

#define MFMA(a, b, c) __builtin_amdgcn_mfma_f32_16x16x32_bf16((a), (b), (c), 0, 0, 0)

// ---- ws float offsets -------------------------------------------------------
#define Q_OFF    0            // 8,388,608 floats
#define Y_OFF    8388608      // 1,638,400
#define KB_OFF   10027008     //   819,200
#define VB_OFF   10846208     //   819,200
#define PART_OFF 11665408     // 1,572,864
#define WSP_OFF  13238272     // 851,968 floats = 1,703,936 u16 (hi+lo)
// total 14,090,240 floats = 56.4 MB

// split-weight region offsets (u16 units, within hi or lo half)
#define OQW 0
#define OPW 16384
#define OS1 32768
#define OS2 557056
#define OS3 688128
#define OS4 819200
#define TOTW 851968

#define GS 520   // LDS frag group stride in u16 (16 rows x 8 + pad, 16B-aligned)

// ---------------------------------------------------------------------------
__device__ __forceinline__ u16 f2bf_rne(float x) {
  unsigned u = __float_as_uint(x);
  return (u16)((u + 0x7FFFu + ((u >> 16) & 1u)) >> 16);
}
__device__ __forceinline__ void split2(float v, u16& h, u16& l) {
  unsigned u = __float_as_uint(v);
  unsigned hb = (u + 0x7FFFu + ((u >> 16) & 1u)) & 0xFFFF0000u;
  h = (u16)(hb >> 16);
  float lf = v - __uint_as_float(hb);
  l = f2bf_rne(lf);
}
__device__ __forceinline__ void split4(float4 v, ushort4& h, ushort4& l) {
  split2(v.x, h.x, l.x); split2(v.y, h.y, l.y);
  split2(v.z, h.z, l.z); split2(v.w, h.w, l.w);
}

// ---------------------------------------------------------------------------
// split weights fp32 -> bf16 hi/lo (all 6 weight matrices, concatenated)
// ---------------------------------------------------------------------------
__global__ __launch_bounds__(256) void split_w_kernel(
    const float* __restrict__ qw, const float* __restrict__ pw,
    const float* __restrict__ s1, const float* __restrict__ s2,
    const float* __restrict__ s3, const float* __restrict__ s4,
    u16* __restrict__ hi, u16* __restrict__ lo) {
  int idx = blockIdx.x * 256 + threadIdx.x;   // grid sized exactly TOTW/256
  const float* src; int off;
  if      (idx < OPW)  { src = qw; off = idx; }
  else if (idx < OS1)  { src = pw; off = idx - OPW; }
  else if (idx < OS2)  { src = s1; off = idx - OS1; }
  else if (idx < OS3)  { src = s2; off = idx - OS2; }
  else if (idx < OS4)  { src = s3; off = idx - OS3; }
  else                 { src = s4; off = idx - OS4; }
  u16 h, l; split2(src[off], h, l);
  hi[idx] = h; lo[idx] = l;
}

// ---------------------------------------------------------------------------
// fused LayerNorm(128) + Q-projection via bf16x3 MFMA. 64 tokens / block.
// ---------------------------------------------------------------------------
__global__ __launch_bounds__(256) void lnq_mfma_kernel(
    const float* __restrict__ inp, const float* __restrict__ nw,
    const float* __restrict__ nb, const u16* __restrict__ wh,
    const u16* __restrict__ wl, const float* __restrict__ qb,
    float* __restrict__ q) {
  __shared__ float xs[128 * 65];
  __shared__ float ps[4][64], ps2[4][64];
  __shared__ float mu[64], rs[64];
  __shared__ __align__(16) u16 xsh[16 * GS];
  __shared__ __align__(16) u16 xsl[16 * GS];
  int bid = blockIdx.x, n = bid >> 8, t0 = (bid & 255) * 64;
  const float* xb = inp + (size_t)n * C_ * HW_;
  for (int idx = threadIdx.x; idx < 8192; idx += 256) {
    int c = idx >> 6, tt = idx & 63;
    xs[c * 65 + tt] = xb[c * HW_ + t0 + tt];
  }
  __syncthreads();
  {
    int tt = threadIdx.x & 63, part = threadIdx.x >> 6;
    float s = 0.f, s2 = 0.f;
    for (int c = part * 32; c < part * 32 + 32; ++c) {
      float v = xs[c * 65 + tt];
      s += v; s2 += v * v;
    }
    ps[part][tt] = s; ps2[part][tt] = s2;
  }
  __syncthreads();
  if (threadIdx.x < 64) {
    int tt = threadIdx.x;
    float s  = ps[0][tt] + ps[1][tt] + ps[2][tt] + ps[3][tt];
    float s2 = ps2[0][tt] + ps2[1][tt] + ps2[2][tt] + ps2[3][tt];
    float m = s * (1.0f / 128.0f);
    float v = s2 * (1.0f / 128.0f) - m * m;
    mu[tt] = m; rs[tt] = rsqrtf(v + 1e-5f);
  }
  __syncthreads();
  for (int idx = threadIdx.x; idx < 8192; idx += 256) {
    int c = idx & 127, tt = idx >> 7;
    float v = (xs[c * 65 + tt] - mu[tt]) * rs[tt] * nw[c] + nb[c];
    u16 h, l; split2(v, h, l);
    int o = (c >> 3) * GS + tt * 8 + (c & 7);
    xsh[o] = h; xsl[o] = l;
  }
  __syncthreads();
  int wid = threadIdx.x >> 6, lane = threadIdx.x & 63;
  int r = lane & 15, g = lane >> 4;
  f32x4 acc[8] = {};
  #pragma unroll
  for (int kk = 0; kk < 4; ++kk) {
    bf16x8 ah = *(const bf16x8*)&xsh[(kk * 4 + g) * GS + (wid * 16 + r) * 8];
    bf16x8 al = *(const bf16x8*)&xsl[(kk * 4 + g) * GS + (wid * 16 + r) * 8];
    #pragma unroll
    for (int ct = 0; ct < 8; ++ct) {
      int o = ct * 16 + r;
      bf16x8 bh = *(const bf16x8*)&wh[o * 128 + kk * 32 + g * 8];
      bf16x8 bl = *(const bf16x8*)&wl[o * 128 + kk * 32 + g * 8];
      acc[ct] = MFMA(ah, bh, acc[ct]);
      acc[ct] = MFMA(ah, bl, acc[ct]);
      acc[ct] = MFMA(al, bh, acc[ct]);
    }
  }
  #pragma unroll
  for (int ct = 0; ct < 8; ++ct) {
    int col = ct * 16 + r;
    #pragma unroll
    for (int reg = 0; reg < 4; ++reg) {
      int row = wid * 16 + g * 4 + reg;
      q[((size_t)n * HW_ + t0 + row) * 128 + col] = acc[ct][reg] + qb[col];
    }
  }
}

// ---------------------------------------------------------------------------
// generic 128-K GEMM via bf16x3 MFMA (final projection, in-place safe)
// ---------------------------------------------------------------------------
__global__ __launch_bounds__(256) void gemm128_mfma_kernel(
    const float* __restrict__ x, const u16* __restrict__ wh,
    const u16* __restrict__ wl, const float* __restrict__ b,
    float* __restrict__ out) {
  __shared__ __align__(16) u16 xsh[16 * GS];
  __shared__ __align__(16) u16 xsl[16 * GS];
  int r0 = blockIdx.x * 64;
  #pragma unroll
  for (int it = 0; it < 8; ++it) {
    int idx4 = it * 256 + threadIdx.x;       // 2048 float4s
    int row = idx4 >> 5, cg = idx4 & 31;
    float4 v = *(const float4*)&x[(size_t)(r0 + row) * 128 + cg * 4];
    ushort4 h4, l4; split4(v, h4, l4);
    int o = (cg >> 1) * GS + row * 8 + (cg & 1) * 4;
    *(ushort4*)&xsh[o] = h4; *(ushort4*)&xsl[o] = l4;
  }
  __syncthreads();
  int wid = threadIdx.x >> 6, lane = threadIdx.x & 63;
  int r = lane & 15, g = lane >> 4;
  f32x4 acc[8] = {};
  #pragma unroll
  for (int kk = 0; kk < 4; ++kk) {
    bf16x8 ah = *(const bf16x8*)&xsh[(kk * 4 + g) * GS + (wid * 16 + r) * 8];
    bf16x8 al = *(const bf16x8*)&xsl[(kk * 4 + g) * GS + (wid * 16 + r) * 8];
    #pragma unroll
    for (int ct = 0; ct < 8; ++ct) {
      int o = ct * 16 + r;
      bf16x8 bh = *(const bf16x8*)&wh[o * 128 + kk * 32 + g * 8];
      bf16x8 bl = *(const bf16x8*)&wl[o * 128 + kk * 32 + g * 8];
      acc[ct] = MFMA(ah, bh, acc[ct]);
      acc[ct] = MFMA(ah, bl, acc[ct]);
      acc[ct] = MFMA(al, bh, acc[ct]);
    }
  }
  #pragma unroll
  for (int ct = 0; ct < 8; ++ct) {
    int col = ct * 16 + r;
    #pragma unroll
    for (int reg = 0; reg < 4; ++reg) {
      int row = r0 + wid * 16 + g * 4 + reg;
      out[(size_t)row * 128 + col] = acc[ct][reg] + b[col];
    }
  }
}

// ---------------------------------------------------------------------------
// conv-as-GEMM via bf16x3 MFMA, fused im2col. BM=64 tokens, N=64, BK=32.
// ---------------------------------------------------------------------------
template <int P, int NW, int SEG>
__device__ __forceinline__ void conv_body(
    int mblk, int seg, const float* __restrict__ inp,
    const u16* __restrict__ wh, const u16* __restrict__ wl,
    float* __restrict__ dst, const float* __restrict__ bias,
    u16* xsh, u16* xsl) {
  constexpr int K    = 128 * P * P;
  constexpr int KSEG = K / SEG;
  constexpr int NT   = KSEG / 32;
  constexpr int HWIN = H_ / NW;
  constexpr int G    = HWIN / P;
  constexpr int L    = G * G;
  constexpr int M    = 4 * NW * NW * L;
  constexpr int LGL  = (L == 256) ? 8 : 6;
  constexpr int LGG  = (G == 16) ? 4 : 3;
  constexpr int LGNW = (NW == 8) ? 3 : (NW == 4) ? 2 : (NW == 2) ? 1 : 0;
  constexpr int LGP  = (P == 8) ? 3 : (P == 4) ? 2 : 1;
  constexpr int LGP2 = 2 * LGP;
  int tid = threadIdx.x, wid = tid >> 6, lane = tid & 63;
  int r = lane & 15, g = lane >> 4;
  int t0 = mblk * 64;
  f32x4 acc[4] = {};
  for (int kt = 0; kt < NT; ++kt) {
    int k0 = seg * KSEG + kt * 32;
    #pragma unroll
    for (int it = 0; it < 2; ++it) {
      int idx = tid + it * 256;
      int row = idx >> 3, kq = idx & 7;
      int tglob = t0 + row;
      int bwin = tglob >> LGL;
      int loc  = tglob & (L - 1);
      int n    = bwin >> (2 * LGNW);
      int wrem = bwin & (NW * NW - 1);
      int wy = wrem >> LGNW, wx = wrem & (NW - 1);
      int oh = loc >> LGG,   ow = loc & (G - 1);
      int k  = k0 + kq * 4;
      int ci = k >> LGP2;
      int wp = k & (P * P - 1);
      int kh = wp >> LGP, kwp = wp & (P - 1);
      int rr = wy * HWIN + oh * P + kh;
      int cc = wx * HWIN + ow * P + kwp;
      const float* src = inp + ((size_t)n * C_ + ci) * HW_ + rr * W_ + cc;
      float4 v;
      if constexpr (P >= 4) {
        v = *(const float4*)src;
      } else {
        float2 a  = *(const float2*)src;
        float2 bb = *(const float2*)(src + W_);
        v = make_float4(a.x, a.y, bb.x, bb.y);
      }
      ushort4 h4, l4; split4(v, h4, l4);
      int o = (kq >> 1) * GS + row * 8 + (kq & 1) * 4;
      *(ushort4*)&xsh[o] = h4; *(ushort4*)&xsl[o] = l4;
    }
    __syncthreads();
    bf16x8 ah = *(const bf16x8*)&xsh[g * GS + (wid * 16 + r) * 8];
    bf16x8 al = *(const bf16x8*)&xsl[g * GS + (wid * 16 + r) * 8];
    #pragma unroll
    for (int ct = 0; ct < 4; ++ct) {
      int o = ct * 16 + r;
      bf16x8 bh = *(const bf16x8*)&wh[(size_t)o * K + k0 + g * 8];
      bf16x8 bl = *(const bf16x8*)&wl[(size_t)o * K + k0 + g * 8];
      acc[ct] = MFMA(ah, bh, acc[ct]);
      acc[ct] = MFMA(ah, bl, acc[ct]);
      acc[ct] = MFMA(al, bh, acc[ct]);
    }
    __syncthreads();
  }
  #pragma unroll
  for (int ct = 0; ct < 4; ++ct) {
    int o = ct * 16 + r;
    #pragma unroll
    for (int reg = 0; reg < 4; ++reg) {
      int row = t0 + wid * 16 + g * 4 + reg;
      if constexpr (SEG == 1) dst[(size_t)row * 64 + o] = acc[ct][reg] + bias[o];
      else                    dst[((size_t)seg * M + row) * 64 + o] = acc[ct][reg];
    }
  }
}

__global__ __launch_bounds__(256) void conv_mfma_kernel(
    const float* __restrict__ inp, const u16* __restrict__ wsh,
    const u16* __restrict__ wsl, const float* __restrict__ b4,
    float* __restrict__ part, float* __restrict__ y) {
  __shared__ __align__(16) u16 xsh[4 * GS];
  __shared__ __align__(16) u16 xsl[4 * GS];
  int bid = blockIdx.x;
  if (bid < 128) {            // head1: 16 mblk x 8 seg
    conv_body<8, 1, 8>(bid & 15, bid >> 4, inp, wsh + OS1, wsl + OS1,
                       part, nullptr, xsh, xsl);
  } else if (bid < 256) {     // head2: 64 mblk x 2 seg
    int lb = bid - 128;
    conv_body<4, 2, 2>(lb & 63, lb >> 6, inp, wsh + OS2, wsl + OS2,
                       part + 524288, nullptr, xsh, xsl);
  } else if (bid < 384) {     // head3: 64 mblk x 2 seg
    int lb = bid - 256;
    conv_body<4, 4, 2>(lb & 63, lb >> 6, inp, wsh + OS3, wsl + OS3,
                       part + 1048576, nullptr, xsh, xsl);
  } else {                    // head4: 256 mblk, direct
    conv_body<2, 8, 1>(bid - 384, 0, inp, wsh + OS4, wsl + OS4,
                       y + (size_t)9216 * 64, b4, xsh, xsl);
  }
}

// reduce K-split partials for heads 1-3
__global__ __launch_bounds__(256) void reduce_kernel(
    const float* __restrict__ part, const float* __restrict__ b1,
    const float* __restrict__ b2, const float* __restrict__ b3,
    float* __restrict__ y) {
  int idx = blockIdx.x * 256 + threadIdx.x;   // grid exactly 589824/256
  int tg = idx >> 6, o = idx & 63;
  float s;
  if (tg < 1024) {
    s = b1[o];
    #pragma unroll
    for (int sg = 0; sg < 8; ++sg) s += part[((size_t)sg * 1024 + tg) * 64 + o];
  } else if (tg < 5120) {
    int t = tg - 1024;
    const float* p2 = part + 524288;
    s = b2[o] + p2[(size_t)t * 64 + o] + p2[((size_t)4096 + t) * 64 + o];
  } else {
    int t = tg - 5120;
    const float* p3 = part + 1048576;
    s = b3[o] + p3[(size_t)t * 64 + o] + p3[((size_t)4096 + t) * 64 + o];
  }
  y[(size_t)tg * 64 + o] = s;
}

// ---------------------------------------------------------------------------
// merged per-token LN(64) + exact GELU + KV projection, all heads
// ---------------------------------------------------------------------------
struct KvArgs { const float* p[16]; };  // [h*4 + {lnw,lnb,kvw,kvb}]

__global__ __launch_bounds__(256) void lnkv_kernel(
    const float* __restrict__ y, KvArgs a,
    float* __restrict__ kbuf, float* __restrict__ vbuf) {
  __shared__ float xg[4][64];
  int wv = threadIdx.x >> 6, lane = threadIdx.x & 63;
  int tg = blockIdx.x * 4 + wv;              // < 25600
  int h = (tg < 1024) ? 0 : (tg < 5120) ? 1 : (tg < 9216) ? 2 : 3;
  const float* lnw = a.p[h * 4 + 0];
  const float* lnb = a.p[h * 4 + 1];
  const float* kvw = a.p[h * 4 + 2];
  const float* kvb = a.p[h * 4 + 3];
  float x = y[(size_t)tg * 64 + lane];
  float s = x;
  for (int m = 1; m < 64; m <<= 1) s += __shfl_xor(s, m, 64);
  float mean = s * (1.0f / 64.0f);
  float d = x - mean;
  float v = d * d;
  for (int m = 1; m < 64; m <<= 1) v += __shfl_xor(v, m, 64);
  v *= (1.0f / 64.0f);
  float xn = d * rsqrtf(v + 1e-5f) * lnw[lane] + lnb[lane];
  float gg = 0.5f * xn * (1.0f + erff(xn * 0.70710678118654752f));
  xg[wv][lane] = gg;
  __syncthreads();
  float acc = kvb[lane];
  const float* wr = kvw + lane * 64;
  #pragma unroll 8
  for (int c = 0; c < 64; ++c) acc += xg[wv][c] * wr[c];
  if (lane < 32) kbuf[(size_t)tg * 32 + lane] = acc;
  else           vbuf[(size_t)tg * 32 + (lane - 32)] = acc;
}

// ---------------------------------------------------------------------------
// merged attention, all heads: thread-per-query online softmax, K/V in LDS
// ---------------------------------------------------------------------------
template <int NW, int LK>
__device__ __forceinline__ void attn_body(
    int bid, int head, int head_off, const float* __restrict__ q,
    const float* __restrict__ kbuf, const float* __restrict__ vbuf,
    float* __restrict__ cbuf) {
  extern __shared__ float asmem[];
  float* kl = asmem;
  float* vl = asmem + LK * 32;
  constexpr int HWIN  = H_ / NW;
  constexpr int TILES = (HWIN * HWIN) / 256;
  int bwin = bid / TILES, tile = bid % TILES;
  int n  = bwin / (NW * NW);
  int wy = (bwin / NW) % NW, wx = bwin % NW;
  const float* kb = kbuf + (size_t)(head_off + bwin * LK) * 32;
  const float* vb = vbuf + (size_t)(head_off + bwin * LK) * 32;
  for (int idx = threadIdx.x; idx < LK * 32; idx += 256) {
    kl[idx] = kb[idx];
    vl[idx] = vb[idx];
  }
  __syncthreads();
  int j  = tile * 256 + threadIdx.x;
  int ih = j / HWIN, iw = j % HWIN;
  int t  = (wy * HWIN + ih) * W_ + wx * HWIN + iw;
  const float* qp = q + ((size_t)n * HW_ + t) * 128 + head * 32;
  float qr[32];
  #pragma unroll
  for (int d2 = 0; d2 < 32; ++d2) qr[d2] = qp[d2];
  float m = -1e30f, l = 0.f;
  float acc[32];
  #pragma unroll
  for (int d2 = 0; d2 < 32; ++d2) acc[d2] = 0.f;
  for (int kk = 0; kk < LK; ++kk) {
    const float* kr = kl + kk * 32;
    float s = 0.f;
    #pragma unroll
    for (int d2 = 0; d2 < 32; ++d2) s += qr[d2] * kr[d2];
    s *= SCALE_;
    float mn   = fmaxf(m, s);
    float corr = __expf(m - mn);
    float e    = __expf(s - mn);
    l = l * corr + e;
    const float* vr = vl + kk * 32;
    #pragma unroll
    for (int d2 = 0; d2 < 32; ++d2) acc[d2] = acc[d2] * corr + e * vr[d2];
    m = mn;
  }
  float inv = 1.0f / l;
  float* op = cbuf + ((size_t)n * HW_ + t) * 128 + head * 32;
  #pragma unroll
  for (int d2 = 0; d2 < 32; ++d2) op[d2] = acc[d2] * inv;
}

__global__ __launch_bounds__(256) void attn_kernel(
    const float* __restrict__ q, const float* __restrict__ kbuf,
    const float* __restrict__ vbuf, float* __restrict__ cbuf) {
  int bid = blockIdx.x;
  if      (bid < 256) attn_body<1, 256>(bid,       0, 0,    q, kbuf, vbuf, cbuf);
  else if (bid < 512) attn_body<2, 256>(bid - 256, 1, 1024, q, kbuf, vbuf, cbuf);
  else if (bid < 768) attn_body<4, 64 >(bid - 512, 2, 5120, q, kbuf, vbuf, cbuf);
  else                attn_body<8, 64 >(bid - 768, 3, 9216, q, kbuf, vbuf, cbuf);
}

// ---------------------------------------------------------------------------
extern "C" void kernel_launch(void* const* d_in, const int* in_sizes, int n_in,
                              void* d_out, int out_size, void* d_ws, size_t ws_size,
                              hipStream_t stream) {
  const float* inp = (const float*)d_in[0];
  const float* nw  = (const float*)d_in[1];
  const float* nb  = (const float*)d_in[2];
  const float* qw  = (const float*)d_in[3];
  const float* qb  = (const float*)d_in[4];
  const float* pw  = (const float*)d_in[29];
  const float* pb  = (const float*)d_in[30];

  float* ws   = (float*)d_ws;
  float* q    = ws + Q_OFF;
  float* y    = ws + Y_OFF;
  float* kbuf = ws + KB_OFF;
  float* vbuf = ws + VB_OFF;
  float* part = ws + PART_OFF;
  u16*   wsp  = (u16*)(ws + WSP_OFF);
  u16*   whi  = wsp;
  u16*   wlo  = wsp + TOTW;
  float* cbuf = (float*)d_out;

  // 0) split all GEMM weights to bf16 hi/lo
  split_w_kernel<<<TOTW / 256, 256, 0, stream>>>(
      qw, pw, (const float*)d_in[5], (const float*)d_in[11],
      (const float*)d_in[17], (const float*)d_in[23], whi, wlo);

  // 1) fused LN + Q projection (MFMA)
  lnq_mfma_kernel<<<1024, 256, 0, stream>>>(inp, nw, nb, whi + OQW, wlo + OQW, qb, q);

  // 2) all 4 patch-embed convs in one launch (MFMA)
  conv_mfma_kernel<<<640, 256, 0, stream>>>(inp, whi, wlo,
                                            (const float*)d_in[24], part, y);

  // 3) reduce K-split partials (heads 1-3)
  reduce_kernel<<<2304, 256, 0, stream>>>(part, (const float*)d_in[6],
                                          (const float*)d_in[12],
                                          (const float*)d_in[18], y);

  // 4) merged LN+GELU+KV projection
  KvArgs ka;
  ka.p[0]  = (const float*)d_in[7];  ka.p[1]  = (const float*)d_in[8];
  ka.p[2]  = (const float*)d_in[9];  ka.p[3]  = (const float*)d_in[10];
  ka.p[4]  = (const float*)d_in[13]; ka.p[5]  = (const float*)d_in[14];
  ka.p[6]  = (const float*)d_in[15]; ka.p[7]  = (const float*)d_in[16];
  ka.p[8]  = (const float*)d_in[19]; ka.p[9]  = (const float*)d_in[20];
  ka.p[10] = (const float*)d_in[21]; ka.p[11] = (const float*)d_in[22];
  ka.p[12] = (const float*)d_in[25]; ka.p[13] = (const float*)d_in[26];
  ka.p[14] = (const float*)d_in[27]; ka.p[15] = (const float*)d_in[28];
  lnkv_kernel<<<6400, 256, 0, stream>>>(y, ka, kbuf, vbuf);

  // 5) merged attention (64 KB dynamic LDS)
  attn_kernel<<<1024, 256, 65536, stream>>>(q, kbuf, vbuf, cbuf);

  // 6) final projection, in place on d_out (MFMA)
  gemm128_mfma_kernel<<<1024, 256, 0, stream>>>(cbuf, whi + OPW, wlo + OPW, pb,
                                                (float*)d_out);
}

// Round 4
// 297.914 us; speedup vs baseline: 7.9084x; 1.5512x over previous
//
#include <hip/hip_runtime.h>
#include <math.h>

#define N_   4
#define C_   128
#define H_   128
#define W_   128
#define HW_  16384
#define SCALE_ 0.17677669529663687f   // 32^-0.5

typedef unsigned short u16;
typedef __bf16 bf16x8 __attribute__((ext_vector_type(8)));
typedef float  f32x4  __attribute__((ext_vector_type(4)));

#define MFMA(a, b, c) __builtin_amdgcn_mfma_f32_16x16x32_bf16((a), (b), (c), 0, 0, 0)

// ---- ws float offsets -------------------------------------------------------
#define Q_OFF    0            // 8,388,608 floats
#define Y_OFF    8388608      // 1,638,400
#define KB_OFF   10027008     //   409,600 floats (819,200 u16 bf16 K)
#define VT_OFF   10436608     //   409,600 floats (819,200 u16 bf16 V^T per win)
#define PART_OFF 10846208     // 1,572,864
#define WSP_OFF  12419072     // 851,968 floats = 1,703,936 u16 (hi+lo)
// total ~13.3M floats = 53 MB

// split-weight region offsets (u16 units, within hi or lo half)
#define OQW 0
#define OPW 16384
#define OS1 32768
#define OS2 557056
#define OS3 688128
#define OS4 819200
#define TOTW 851968

#define GS 520   // LDS frag group stride in u16 (16 rows x 8 + pad, 16B-aligned)

// ---------------------------------------------------------------------------
__device__ __forceinline__ u16 f2bf_rne(float x) {
  unsigned u = __float_as_uint(x);
  return (u16)((u + 0x7FFFu + ((u >> 16) & 1u)) >> 16);
}
__device__ __forceinline__ void split2(float v, u16& h, u16& l) {
  unsigned u = __float_as_uint(v);
  unsigned hb = (u + 0x7FFFu + ((u >> 16) & 1u)) & 0xFFFF0000u;
  h = (u16)(hb >> 16);
  float lf = v - __uint_as_float(hb);
  l = f2bf_rne(lf);
}
__device__ __forceinline__ void split4(float4 v, ushort4& h, ushort4& l) {
  split2(v.x, h.x, l.x); split2(v.y, h.y, l.y);
  split2(v.z, h.z, l.z); split2(v.w, h.w, l.w);
}

// ---------------------------------------------------------------------------
// split weights fp32 -> bf16 hi/lo (all 6 weight matrices, concatenated)
// ---------------------------------------------------------------------------
__global__ __launch_bounds__(256) void split_w_kernel(
    const float* __restrict__ qw, const float* __restrict__ pw,
    const float* __restrict__ s1, const float* __restrict__ s2,
    const float* __restrict__ s3, const float* __restrict__ s4,
    u16* __restrict__ hi, u16* __restrict__ lo) {
  int idx = blockIdx.x * 256 + threadIdx.x;   // grid sized exactly TOTW/256
  const float* src; int off;
  if      (idx < OPW)  { src = qw; off = idx; }
  else if (idx < OS1)  { src = pw; off = idx - OPW; }
  else if (idx < OS2)  { src = s1; off = idx - OS1; }
  else if (idx < OS3)  { src = s2; off = idx - OS2; }
  else if (idx < OS4)  { src = s3; off = idx - OS3; }
  else                 { src = s4; off = idx - OS4; }
  u16 h, l; split2(src[off], h, l);
  hi[idx] = h; lo[idx] = l;
}

// ---------------------------------------------------------------------------
// fused LayerNorm(128) + Q-projection via bf16x3 MFMA. 64 tokens / block.
// ---------------------------------------------------------------------------
__global__ __launch_bounds__(256) void lnq_mfma_kernel(
    const float* __restrict__ inp, const float* __restrict__ nw,
    const float* __restrict__ nb, const u16* __restrict__ wh,
    const u16* __restrict__ wl, const float* __restrict__ qb,
    float* __restrict__ q) {
  __shared__ float xs[128 * 65];
  __shared__ float ps[4][64], ps2[4][64];
  __shared__ float mu[64], rs[64];
  __shared__ __align__(16) u16 xsh[16 * GS];
  __shared__ __align__(16) u16 xsl[16 * GS];
  int bid = blockIdx.x, n = bid >> 8, t0 = (bid & 255) * 64;
  const float* xb = inp + (size_t)n * C_ * HW_;
  for (int idx = threadIdx.x; idx < 8192; idx += 256) {
    int c = idx >> 6, tt = idx & 63;
    xs[c * 65 + tt] = xb[c * HW_ + t0 + tt];
  }
  __syncthreads();
  {
    int tt = threadIdx.x & 63, part = threadIdx.x >> 6;
    float s = 0.f, s2 = 0.f;
    for (int c = part * 32; c < part * 32 + 32; ++c) {
      float v = xs[c * 65 + tt];
      s += v; s2 += v * v;
    }
    ps[part][tt] = s; ps2[part][tt] = s2;
  }
  __syncthreads();
  if (threadIdx.x < 64) {
    int tt = threadIdx.x;
    float s  = ps[0][tt] + ps[1][tt] + ps[2][tt] + ps[3][tt];
    float s2 = ps2[0][tt] + ps2[1][tt] + ps2[2][tt] + ps2[3][tt];
    float m = s * (1.0f / 128.0f);
    float v = s2 * (1.0f / 128.0f) - m * m;
    mu[tt] = m; rs[tt] = rsqrtf(v + 1e-5f);
  }
  __syncthreads();
  for (int idx = threadIdx.x; idx < 8192; idx += 256) {
    int c = idx & 127, tt = idx >> 7;
    float v = (xs[c * 65 + tt] - mu[tt]) * rs[tt] * nw[c] + nb[c];
    u16 h, l; split2(v, h, l);
    int o = (c >> 3) * GS + tt * 8 + (c & 7);
    xsh[o] = h; xsl[o] = l;
  }
  __syncthreads();
  int wid = threadIdx.x >> 6, lane = threadIdx.x & 63;
  int r = lane & 15, g = lane >> 4;
  f32x4 acc[8] = {};
  #pragma unroll
  for (int kk = 0; kk < 4; ++kk) {
    bf16x8 ah = *(const bf16x8*)&xsh[(kk * 4 + g) * GS + (wid * 16 + r) * 8];
    bf16x8 al = *(const bf16x8*)&xsl[(kk * 4 + g) * GS + (wid * 16 + r) * 8];
    #pragma unroll
    for (int ct = 0; ct < 8; ++ct) {
      int o = ct * 16 + r;
      bf16x8 bh = *(const bf16x8*)&wh[o * 128 + kk * 32 + g * 8];
      bf16x8 bl = *(const bf16x8*)&wl[o * 128 + kk * 32 + g * 8];
      acc[ct] = MFMA(ah, bh, acc[ct]);
      acc[ct] = MFMA(ah, bl, acc[ct]);
      acc[ct] = MFMA(al, bh, acc[ct]);
    }
  }
  #pragma unroll
  for (int ct = 0; ct < 8; ++ct) {
    int col = ct * 16 + r;
    #pragma unroll
    for (int reg = 0; reg < 4; ++reg) {
      int row = wid * 16 + g * 4 + reg;
      q[((size_t)n * HW_ + t0 + row) * 128 + col] = acc[ct][reg] + qb[col];
    }
  }
}

// ---------------------------------------------------------------------------
// generic 128-K GEMM via bf16x3 MFMA (final projection, in-place safe)
// ---------------------------------------------------------------------------
__global__ __launch_bounds__(256) void gemm128_mfma_kernel(
    const float* __restrict__ x, const u16* __restrict__ wh,
    const u16* __restrict__ wl, const float* __restrict__ b,
    float* __restrict__ out) {
  __shared__ __align__(16) u16 xsh[16 * GS];
  __shared__ __align__(16) u16 xsl[16 * GS];
  int r0 = blockIdx.x * 64;
  #pragma unroll
  for (int it = 0; it < 8; ++it) {
    int idx4 = it * 256 + threadIdx.x;       // 2048 float4s
    int row = idx4 >> 5, cg = idx4 & 31;
    float4 v = *(const float4*)&x[(size_t)(r0 + row) * 128 + cg * 4];
    ushort4 h4, l4; split4(v, h4, l4);
    int o = (cg >> 1) * GS + row * 8 + (cg & 1) * 4;
    *(ushort4*)&xsh[o] = h4; *(ushort4*)&xsl[o] = l4;
  }
  __syncthreads();
  int wid = threadIdx.x >> 6, lane = threadIdx.x & 63;
  int r = lane & 15, g = lane >> 4;
  f32x4 acc[8] = {};
  #pragma unroll
  for (int kk = 0; kk < 4; ++kk) {
    bf16x8 ah = *(const bf16x8*)&xsh[(kk * 4 + g) * GS + (wid * 16 + r) * 8];
    bf16x8 al = *(const bf16x8*)&xsl[(kk * 4 + g) * GS + (wid * 16 + r) * 8];
    #pragma unroll
    for (int ct = 0; ct < 8; ++ct) {
      int o = ct * 16 + r;
      bf16x8 bh = *(const bf16x8*)&wh[o * 128 + kk * 32 + g * 8];
      bf16x8 bl = *(const bf16x8*)&wl[o * 128 + kk * 32 + g * 8];
      acc[ct] = MFMA(ah, bh, acc[ct]);
      acc[ct] = MFMA(ah, bl, acc[ct]);
      acc[ct] = MFMA(al, bh, acc[ct]);
    }
  }
  #pragma unroll
  for (int ct = 0; ct < 8; ++ct) {
    int col = ct * 16 + r;
    #pragma unroll
    for (int reg = 0; reg < 4; ++reg) {
      int row = r0 + wid * 16 + g * 4 + reg;
      out[(size_t)row * 128 + col] = acc[ct][reg] + b[col];
    }
  }
}

// ---------------------------------------------------------------------------
// conv-as-GEMM via bf16x3 MFMA, fused im2col. BM=64 tokens, N=64, BK=32.
// ---------------------------------------------------------------------------
template <int P, int NW, int SEG>
__device__ __forceinline__ void conv_body(
    int mblk, int seg, const float* __restrict__ inp,
    const u16* __restrict__ wh, const u16* __restrict__ wl,
    float* __restrict__ dst, const float* __restrict__ bias,
    u16* xsh, u16* xsl) {
  constexpr int K    = 128 * P * P;
  constexpr int KSEG = K / SEG;
  constexpr int NT   = KSEG / 32;
  constexpr int HWIN = H_ / NW;
  constexpr int G    = HWIN / P;
  constexpr int L    = G * G;
  constexpr int M    = 4 * NW * NW * L;
  constexpr int LGL  = (L == 256) ? 8 : 6;
  constexpr int LGG  = (G == 16) ? 4 : 3;
  constexpr int LGNW = (NW == 8) ? 3 : (NW == 4) ? 2 : (NW == 2) ? 1 : 0;
  constexpr int LGP  = (P == 8) ? 3 : (P == 4) ? 2 : 1;
  constexpr int LGP2 = 2 * LGP;
  int tid = threadIdx.x, wid = tid >> 6, lane = tid & 63;
  int r = lane & 15, g = lane >> 4;
  int t0 = mblk * 64;
  f32x4 acc[4] = {};
  for (int kt = 0; kt < NT; ++kt) {
    int k0 = seg * KSEG + kt * 32;
    #pragma unroll
    for (int it = 0; it < 2; ++it) {
      int idx = tid + it * 256;
      int row = idx >> 3, kq = idx & 7;
      int tglob = t0 + row;
      int bwin = tglob >> LGL;
      int loc  = tglob & (L - 1);
      int n    = bwin >> (2 * LGNW);
      int wrem = bwin & (NW * NW - 1);
      int wy = wrem >> LGNW, wx = wrem & (NW - 1);
      int oh = loc >> LGG,   ow = loc & (G - 1);
      int k  = k0 + kq * 4;
      int ci = k >> LGP2;
      int wp = k & (P * P - 1);
      int kh = wp >> LGP, kwp = wp & (P - 1);
      int rr = wy * HWIN + oh * P + kh;
      int cc = wx * HWIN + ow * P + kwp;
      const float* src = inp + ((size_t)n * C_ + ci) * HW_ + rr * W_ + cc;
      float4 v;
      if constexpr (P >= 4) {
        v = *(const float4*)src;
      } else {
        float2 a  = *(const float2*)src;
        float2 bb = *(const float2*)(src + W_);
        v = make_float4(a.x, a.y, bb.x, bb.y);
      }
      ushort4 h4, l4; split4(v, h4, l4);
      int o = (kq >> 1) * GS + row * 8 + (kq & 1) * 4;
      *(ushort4*)&xsh[o] = h4; *(ushort4*)&xsl[o] = l4;
    }
    __syncthreads();
    bf16x8 ah = *(const bf16x8*)&xsh[g * GS + (wid * 16 + r) * 8];
    bf16x8 al = *(const bf16x8*)&xsl[g * GS + (wid * 16 + r) * 8];
    #pragma unroll
    for (int ct = 0; ct < 4; ++ct) {
      int o = ct * 16 + r;
      bf16x8 bh = *(const bf16x8*)&wh[(size_t)o * K + k0 + g * 8];
      bf16x8 bl = *(const bf16x8*)&wl[(size_t)o * K + k0 + g * 8];
      acc[ct] = MFMA(ah, bh, acc[ct]);
      acc[ct] = MFMA(ah, bl, acc[ct]);
      acc[ct] = MFMA(al, bh, acc[ct]);
    }
    __syncthreads();
  }
  #pragma unroll
  for (int ct = 0; ct < 4; ++ct) {
    int o = ct * 16 + r;
    #pragma unroll
    for (int reg = 0; reg < 4; ++reg) {
      int row = t0 + wid * 16 + g * 4 + reg;
      if constexpr (SEG == 1) dst[(size_t)row * 64 + o] = acc[ct][reg] + bias[o];
      else                    dst[((size_t)seg * M + row) * 64 + o] = acc[ct][reg];
    }
  }
}

__global__ __launch_bounds__(256) void conv_mfma_kernel(
    const float* __restrict__ inp, const u16* __restrict__ wsh,
    const u16* __restrict__ wsl, const float* __restrict__ b4,
    float* __restrict__ part, float* __restrict__ y) {
  __shared__ __align__(16) u16 xsh[4 * GS];
  __shared__ __align__(16) u16 xsl[4 * GS];
  int bid = blockIdx.x;
  if (bid < 128) {            // head1: 16 mblk x 8 seg
    conv_body<8, 1, 8>(bid & 15, bid >> 4, inp, wsh + OS1, wsl + OS1,
                       part, nullptr, xsh, xsl);
  } else if (bid < 256) {     // head2: 64 mblk x 2 seg
    int lb = bid - 128;
    conv_body<4, 2, 2>(lb & 63, lb >> 6, inp, wsh + OS2, wsl + OS2,
                       part + 524288, nullptr, xsh, xsl);
  } else if (bid < 384) {     // head3: 64 mblk x 2 seg
    int lb = bid - 256;
    conv_body<4, 4, 2>(lb & 63, lb >> 6, inp, wsh + OS3, wsl + OS3,
                       part + 1048576, nullptr, xsh, xsl);
  } else {                    // head4: 256 mblk, direct
    conv_body<2, 8, 1>(bid - 384, 0, inp, wsh + OS4, wsl + OS4,
                       y + (size_t)9216 * 64, b4, xsh, xsl);
  }
}

// reduce K-split partials for heads 1-3
__global__ __launch_bounds__(256) void reduce_kernel(
    const float* __restrict__ part, const float* __restrict__ b1,
    const float* __restrict__ b2, const float* __restrict__ b3,
    float* __restrict__ y) {
  int idx = blockIdx.x * 256 + threadIdx.x;   // grid exactly 589824/256
  int tg = idx >> 6, o = idx & 63;
  float s;
  if (tg < 1024) {
    s = b1[o];
    #pragma unroll
    for (int sg = 0; sg < 8; ++sg) s += part[((size_t)sg * 1024 + tg) * 64 + o];
  } else if (tg < 5120) {
    int t = tg - 1024;
    const float* p2 = part + 524288;
    s = b2[o] + p2[(size_t)t * 64 + o] + p2[((size_t)4096 + t) * 64 + o];
  } else {
    int t = tg - 5120;
    const float* p3 = part + 1048576;
    s = b3[o] + p3[(size_t)t * 64 + o] + p3[((size_t)4096 + t) * 64 + o];
  }
  y[(size_t)tg * 64 + o] = s;
}

// ---------------------------------------------------------------------------
// merged per-token LN(64) + exact GELU + KV projection, all heads.
// K written as bf16 [token][32]; V written bf16 window-transposed [d][k].
// ---------------------------------------------------------------------------
struct KvArgs { const float* p[16]; };  // [h*4 + {lnw,lnb,kvw,kvb}]

__global__ __launch_bounds__(256) void lnkv_kernel(
    const float* __restrict__ y, KvArgs a,
    u16* __restrict__ kb, u16* __restrict__ vbT) {
  __shared__ float xg[4][64];
  int wv = threadIdx.x >> 6, lane = threadIdx.x & 63;
  int tg = blockIdx.x * 4 + wv;              // < 25600
  int h = (tg < 1024) ? 0 : (tg < 5120) ? 1 : (tg < 9216) ? 2 : 3;
  const float* lnw = a.p[h * 4 + 0];
  const float* lnb = a.p[h * 4 + 1];
  const float* kvw = a.p[h * 4 + 2];
  const float* kvb = a.p[h * 4 + 3];
  float x = y[(size_t)tg * 64 + lane];
  float s = x;
  for (int m = 1; m < 64; m <<= 1) s += __shfl_xor(s, m, 64);
  float mean = s * (1.0f / 64.0f);
  float d = x - mean;
  float v = d * d;
  for (int m = 1; m < 64; m <<= 1) v += __shfl_xor(v, m, 64);
  v *= (1.0f / 64.0f);
  float xn = d * rsqrtf(v + 1e-5f) * lnw[lane] + lnb[lane];
  float gg = 0.5f * xn * (1.0f + erff(xn * 0.70710678118654752f));
  xg[wv][lane] = gg;
  __syncthreads();
  float acc = kvb[lane];
  const float* wr = kvw + lane * 64;
  #pragma unroll 8
  for (int c = 0; c < 64; ++c) acc += xg[wv][c] * wr[c];
  if (lane < 32) {
    kb[(size_t)tg * 32 + lane] = f2bf_rne(acc);
  } else {
    int dd = lane - 32;
    int lk   = (h < 2) ? 256 : 64;
    int base = (h == 0) ? 0 : (h == 1) ? 1024 : (h == 2) ? 5120 : 9216;
    int kl = (tg - base) & (lk - 1);
    int wstart = tg - kl;
    vbT[(size_t)wstart * 32 + dd * lk + kl] = f2bf_rne(acc);
  }
}

// ---------------------------------------------------------------------------
// MFMA attention: per wave one 16-q tile vs full window key set (exact softmax)
// ---------------------------------------------------------------------------
template <int NW, int LK>
__device__ __forceinline__ void attn_mfma_body(
    int bid, int head, int head_off, const float* __restrict__ q,
    const u16* __restrict__ kb, const u16* __restrict__ vbT,
    float* __restrict__ cbuf) {
  constexpr int HWIN = H_ / NW;
  constexpr int LQ   = HWIN * HWIN;       // queries per window
  constexpr int BPW  = LQ / 64;           // blocks per window
  constexpr int NCT  = LK / 16;           // S col tiles
  constexpr int NST  = LK / 32;           // PV k steps
  constexpr int PS   = LK + 8;            // P LDS row stride (u16)
  extern __shared__ __align__(16) u16 plds[];
  int wid = threadIdx.x >> 6, lane = threadIdx.x & 63;
  int g = lane >> 4, c = lane & 15;
  int win  = bid / BPW;
  int tIdx = (bid % BPW) * 4 + wid;
  int n = win / (NW * NW);
  int wrem = win % (NW * NW);
  int wy = wrem / NW, wx = wrem % NW;
  int kstart = head_off + win * LK;
  u16* pw_ = plds + wid * 16 * PS;

  // Q A-frag: row = c (q local = tIdx*16+c), contraction d = g*8..+7
  int j = tIdx * 16 + c;
  int ih = j / HWIN, iw = j % HWIN;
  int t = (wy * HWIN + ih) * W_ + wx * HWIN + iw;
  const float* qp = q + ((size_t)n * HW_ + t) * 128 + head * 32 + g * 8;
  float4 q0 = *(const float4*)qp;
  float4 q1 = *(const float4*)(qp + 4);
  bf16x8 qa;
  { ushort4 a4, b4u;
    a4.x = f2bf_rne(q0.x); a4.y = f2bf_rne(q0.y); a4.z = f2bf_rne(q0.z); a4.w = f2bf_rne(q0.w);
    b4u.x = f2bf_rne(q1.x); b4u.y = f2bf_rne(q1.y); b4u.z = f2bf_rne(q1.z); b4u.w = f2bf_rne(q1.w);
    union { ushort4 u[2]; bf16x8 b; } cv; cv.u[0] = a4; cv.u[1] = b4u; qa = cv.b; }

  // S = Q K^T  (B-frag: col = key = c, contraction d = g*8..+7)
  f32x4 sacc[NCT];
  #pragma unroll
  for (int ct = 0; ct < NCT; ++ct) {
    sacc[ct] = f32x4{0.f, 0.f, 0.f, 0.f};
    bf16x8 kf = *(const bf16x8*)&kb[(size_t)(kstart + ct * 16 + c) * 32 + g * 8];
    sacc[ct] = MFMA(qa, kf, sacc[ct]);
  }
  // scale
  #pragma unroll
  for (int ct = 0; ct < NCT; ++ct)
    #pragma unroll
    for (int reg = 0; reg < 4; ++reg) sacc[ct][reg] *= SCALE_;
  // softmax per row (row = g*4+reg; cols spread over ct regs x 16 lanes of group g)
  #pragma unroll
  for (int reg = 0; reg < 4; ++reg) {
    float mx = -1e30f;
    #pragma unroll
    for (int ct = 0; ct < NCT; ++ct) mx = fmaxf(mx, sacc[ct][reg]);
    mx = fmaxf(mx, __shfl_xor(mx, 1, 64));
    mx = fmaxf(mx, __shfl_xor(mx, 2, 64));
    mx = fmaxf(mx, __shfl_xor(mx, 4, 64));
    mx = fmaxf(mx, __shfl_xor(mx, 8, 64));
    float sm = 0.f;
    #pragma unroll
    for (int ct = 0; ct < NCT; ++ct) {
      float e = __expf(sacc[ct][reg] - mx);
      sacc[ct][reg] = e;
      sm += e;
    }
    sm += __shfl_xor(sm, 1, 64);
    sm += __shfl_xor(sm, 2, 64);
    sm += __shfl_xor(sm, 4, 64);
    sm += __shfl_xor(sm, 8, 64);
    float inv = 1.0f / sm;
    #pragma unroll
    for (int ct = 0; ct < NCT; ++ct) sacc[ct][reg] *= inv;
  }
  // P -> bf16 into per-wave LDS [16 q][LK k], padded stride
  #pragma unroll
  for (int ct = 0; ct < NCT; ++ct)
    #pragma unroll
    for (int reg = 0; reg < 4; ++reg)
      pw_[(g * 4 + reg) * PS + ct * 16 + c] = f2bf_rne(sacc[ct][reg]);
  // PV: O[q][d] += P[q][k] V[k][d]; A-frag row=q=c, B-frag col=d=c
  f32x4 oacc[2] = {};
  #pragma unroll
  for (int st = 0; st < NST; ++st) {
    bf16x8 pa = *(const bf16x8*)&pw_[c * PS + st * 32 + g * 8];
    #pragma unroll
    for (int dt = 0; dt < 2; ++dt) {
      bf16x8 vf = *(const bf16x8*)&vbT[(size_t)kstart * 32 +
                                       (dt * 16 + c) * LK + st * 32 + g * 8];
      oacc[dt] = MFMA(pa, vf, oacc[dt]);
    }
  }
  // write O (C layout: col=c -> d, row=g*4+reg -> q local)
  #pragma unroll
  for (int reg = 0; reg < 4; ++reg) {
    int jo = tIdx * 16 + g * 4 + reg;
    int iho = jo / HWIN, iwo = jo % HWIN;
    int to = (wy * HWIN + iho) * W_ + wx * HWIN + iwo;
    float* op = cbuf + ((size_t)n * HW_ + to) * 128 + head * 32;
    op[c]      = oacc[0][reg];
    op[16 + c] = oacc[1][reg];
  }
}

__global__ __launch_bounds__(256) void attn_kernel(
    const float* __restrict__ q, const u16* __restrict__ kb,
    const u16* __restrict__ vbT, float* __restrict__ cbuf) {
  int bid = blockIdx.x;
  if      (bid < 1024) attn_mfma_body<1, 256>(bid,        0, 0,    q, kb, vbT, cbuf);
  else if (bid < 2048) attn_mfma_body<2, 256>(bid - 1024, 1, 1024, q, kb, vbT, cbuf);
  else if (bid < 3072) attn_mfma_body<4, 64 >(bid - 2048, 2, 5120, q, kb, vbT, cbuf);
  else                 attn_mfma_body<8, 64 >(bid - 3072, 3, 9216, q, kb, vbT, cbuf);
}

// ---------------------------------------------------------------------------
extern "C" void kernel_launch(void* const* d_in, const int* in_sizes, int n_in,
                              void* d_out, int out_size, void* d_ws, size_t ws_size,
                              hipStream_t stream) {
  const float* inp = (const float*)d_in[0];
  const float* nw  = (const float*)d_in[1];
  const float* nb  = (const float*)d_in[2];
  const float* qw  = (const float*)d_in[3];
  const float* qb  = (const float*)d_in[4];
  const float* pw  = (const float*)d_in[29];
  const float* pb  = (const float*)d_in[30];

  float* ws   = (float*)d_ws;
  float* q    = ws + Q_OFF;
  float* y    = ws + Y_OFF;
  u16*   kb   = (u16*)(ws + KB_OFF);
  u16*   vbT  = (u16*)(ws + VT_OFF);
  float* part = ws + PART_OFF;
  u16*   wsp  = (u16*)(ws + WSP_OFF);
  u16*   whi  = wsp;
  u16*   wlo  = wsp + TOTW;
  float* cbuf = (float*)d_out;

  // 0) split all GEMM weights to bf16 hi/lo
  split_w_kernel<<<TOTW / 256, 256, 0, stream>>>(
      qw, pw, (const float*)d_in[5], (const float*)d_in[11],
      (const float*)d_in[17], (const float*)d_in[23], whi, wlo);

  // 1) fused LN + Q projection (MFMA)
  lnq_mfma_kernel<<<1024, 256, 0, stream>>>(inp, nw, nb, whi + OQW, wlo + OQW, qb, q);

  // 2) all 4 patch-embed convs in one launch (MFMA)
  conv_mfma_kernel<<<640, 256, 0, stream>>>(inp, whi, wlo,
                                            (const float*)d_in[24], part, y);

  // 3) reduce K-split partials (heads 1-3)
  reduce_kernel<<<2304, 256, 0, stream>>>(part, (const float*)d_in[6],
                                          (const float*)d_in[12],
                                          (const float*)d_in[18], y);

  // 4) merged LN+GELU+KV projection (bf16 K, window-transposed bf16 V)
  KvArgs ka;
  ka.p[0]  = (const float*)d_in[7];  ka.p[1]  = (const float*)d_in[8];
  ka.p[2]  = (const float*)d_in[9];  ka.p[3]  = (const float*)d_in[10];
  ka.p[4]  = (const float*)d_in[13]; ka.p[5]  = (const float*)d_in[14];
  ka.p[6]  = (const float*)d_in[15]; ka.p[7]  = (const float*)d_in[16];
  ka.p[8]  = (const float*)d_in[19]; ka.p[9]  = (const float*)d_in[20];
  ka.p[10] = (const float*)d_in[21]; ka.p[11] = (const float*)d_in[22];
  ka.p[12] = (const float*)d_in[25]; ka.p[13] = (const float*)d_in[26];
  ka.p[14] = (const float*)d_in[27]; ka.p[15] = (const float*)d_in[28];
  lnkv_kernel<<<6400, 256, 0, stream>>>(y, ka, kb, vbT);

  // 5) MFMA attention (per-wave P tile in LDS: 4 * 16 * 264 * 2 = 33792 B)
  attn_kernel<<<4096, 256, 33792, stream>>>(q, kb, vbT, cbuf);

  // 6) final projection, in place on d_out (MFMA)
  gemm128_mfma_kernel<<<1024, 256, 0, stream>>>(cbuf, whi + OPW, wlo + OPW, pb,
                                                (float*)d_out);
}

// Round 5
// 249.267 us; speedup vs baseline: 9.4518x; 1.1952x over previous
//
#include <hip/hip_runtime.h>
#include <math.h>

#define N_   4
#define C_   128
#define H_   128
#define W_   128
#define HW_  16384
#define SCALE_ 0.17677669529663687f   // 32^-0.5

typedef unsigned short u16;
typedef unsigned int   u32;
typedef __bf16 bf16x8 __attribute__((ext_vector_type(8)));
typedef float  f32x4  __attribute__((ext_vector_type(4)));

#define MFMA(a, b, c) __builtin_amdgcn_mfma_f32_16x16x32_bf16((a), (b), (c), 0, 0, 0)

// ---- ws float offsets -------------------------------------------------------
#define QB_OFF   0            // 4,194,304 floats (8,388,608 u16 bf16 q)
#define Y_OFF    4194304      // 1,638,400
#define KB_OFF   5832704      //   409,600 floats (819,200 u16 bf16 K)
#define VT_OFF   6242304      //   409,600 floats (819,200 u16 bf16 V^T)
#define PART_OFF 6651904      // 3,145,728
#define WSP_OFF  9797632      //   851,968 floats (2 x 851,968 u16 hi+lo)
#define INH_OFF  10649600     // 4,194,304 floats (8,388,608 u16)
#define INL_OFF  14843904     // 4,194,304 floats
// total 19,038,208 floats = 76.2 MB

// split-weight region offsets (u16 units, within hi or lo half)
#define OQW 0
#define OPW 16384
#define OS1 32768
#define OS2 557056
#define OS3 688128
#define OS4 819200
#define TOTW 851968

#define GS 520   // A-LDS kgroup stride in u16

// ---------------------------------------------------------------------------
__device__ __forceinline__ u16 f2bf_rne(float x) {
  unsigned u = __float_as_uint(x);
  return (u16)((u + 0x7FFFu + ((u >> 16) & 1u)) >> 16);
}
__device__ __forceinline__ void split2(float v, u16& h, u16& l) {
  unsigned u = __float_as_uint(v);
  unsigned hb = (u + 0x7FFFu + ((u >> 16) & 1u)) & 0xFFFF0000u;
  h = (u16)(hb >> 16);
  float lf = v - __uint_as_float(hb);
  l = f2bf_rne(lf);
}
__device__ __forceinline__ void split4(float4 v, ushort4& h, ushort4& l) {
  split2(v.x, h.x, l.x); split2(v.y, h.y, l.y);
  split2(v.z, h.z, l.z); split2(v.w, h.w, l.w);
}

// ---------------------------------------------------------------------------
// split weights fp32 -> bf16 hi/lo (all 6 weight matrices, concatenated)
// ---------------------------------------------------------------------------
__global__ __launch_bounds__(256) void split_w_kernel(
    const float* __restrict__ qw, const float* __restrict__ pw,
    const float* __restrict__ s1, const float* __restrict__ s2,
    const float* __restrict__ s3, const float* __restrict__ s4,
    u16* __restrict__ hi, u16* __restrict__ lo) {
  int idx = blockIdx.x * 256 + threadIdx.x;   // grid sized exactly TOTW/256
  const float* src; int off;
  if      (idx < OPW)  { src = qw; off = idx; }
  else if (idx < OS1)  { src = pw; off = idx - OPW; }
  else if (idx < OS2)  { src = s1; off = idx - OS1; }
  else if (idx < OS3)  { src = s2; off = idx - OS2; }
  else if (idx < OS4)  { src = s3; off = idx - OS3; }
  else                 { src = s4; off = idx - OS4; }
  u16 h, l; split2(src[off], h, l);
  hi[idx] = h; lo[idx] = l;
}

// ---------------------------------------------------------------------------
// pre-split input fp32 -> bf16 hi/lo (memory-bound pass)
// ---------------------------------------------------------------------------
__global__ __launch_bounds__(256) void presplit_kernel(
    const float* __restrict__ inp, u16* __restrict__ h, u16* __restrict__ l) {
  int idx = blockIdx.x * 256 + threadIdx.x;   // float4 units; grid = 8192
  float4 v = *(const float4*)&inp[(size_t)idx * 4];
  ushort4 h4, l4; split4(v, h4, l4);
  *(ushort4*)&h[(size_t)idx * 4] = h4;
  *(ushort4*)&l[(size_t)idx * 4] = l4;
}

// ---------------------------------------------------------------------------
// fused LayerNorm(128) + Q-projection via bf16x3 MFMA -> bf16 q out
// ---------------------------------------------------------------------------
__global__ __launch_bounds__(256) void lnq_mfma_kernel(
    const float* __restrict__ inp, const float* __restrict__ nw,
    const float* __restrict__ nb, const u16* __restrict__ wh,
    const u16* __restrict__ wl, const float* __restrict__ qb,
    u16* __restrict__ q) {
  __shared__ float xs[128 * 65];
  __shared__ float ps[4][64], ps2[4][64];
  __shared__ float mu[64], rs[64];
  __shared__ __align__(16) u16 xsh[16 * GS];
  __shared__ __align__(16) u16 xsl[16 * GS];
  int bid = blockIdx.x, n = bid >> 8, t0 = (bid & 255) * 64;
  const float* xb = inp + (size_t)n * C_ * HW_;
  for (int idx = threadIdx.x; idx < 8192; idx += 256) {
    int c = idx >> 6, tt = idx & 63;
    xs[c * 65 + tt] = xb[c * HW_ + t0 + tt];
  }
  __syncthreads();
  {
    int tt = threadIdx.x & 63, part = threadIdx.x >> 6;
    float s = 0.f, s2 = 0.f;
    for (int c = part * 32; c < part * 32 + 32; ++c) {
      float v = xs[c * 65 + tt];
      s += v; s2 += v * v;
    }
    ps[part][tt] = s; ps2[part][tt] = s2;
  }
  __syncthreads();
  if (threadIdx.x < 64) {
    int tt = threadIdx.x;
    float s  = ps[0][tt] + ps[1][tt] + ps[2][tt] + ps[3][tt];
    float s2 = ps2[0][tt] + ps2[1][tt] + ps2[2][tt] + ps2[3][tt];
    float m = s * (1.0f / 128.0f);
    float v = s2 * (1.0f / 128.0f) - m * m;
    mu[tt] = m; rs[tt] = rsqrtf(v + 1e-5f);
  }
  __syncthreads();
  for (int idx = threadIdx.x; idx < 8192; idx += 256) {
    int c = idx & 127, tt = idx >> 7;
    float v = (xs[c * 65 + tt] - mu[tt]) * rs[tt] * nw[c] + nb[c];
    u16 h, l; split2(v, h, l);
    int o = (c >> 3) * GS + tt * 8 + (c & 7);
    xsh[o] = h; xsl[o] = l;
  }
  __syncthreads();
  int wid = threadIdx.x >> 6, lane = threadIdx.x & 63;
  int r = lane & 15, g = lane >> 4;
  f32x4 acc[8] = {};
  #pragma unroll
  for (int kk = 0; kk < 4; ++kk) {
    bf16x8 ah = *(const bf16x8*)&xsh[(kk * 4 + g) * GS + (wid * 16 + r) * 8];
    bf16x8 al = *(const bf16x8*)&xsl[(kk * 4 + g) * GS + (wid * 16 + r) * 8];
    #pragma unroll
    for (int ct = 0; ct < 8; ++ct) {
      int o = ct * 16 + r;
      bf16x8 bh = *(const bf16x8*)&wh[o * 128 + kk * 32 + g * 8];
      bf16x8 bl = *(const bf16x8*)&wl[o * 128 + kk * 32 + g * 8];
      acc[ct] = MFMA(ah, bh, acc[ct]);
      acc[ct] = MFMA(ah, bl, acc[ct]);
      acc[ct] = MFMA(al, bh, acc[ct]);
    }
  }
  #pragma unroll
  for (int ct = 0; ct < 8; ++ct) {
    int col = ct * 16 + r;
    #pragma unroll
    for (int reg = 0; reg < 4; ++reg) {
      int row = wid * 16 + g * 4 + reg;
      q[((size_t)n * HW_ + t0 + row) * 128 + col] = f2bf_rne(acc[ct][reg] + qb[col]);
    }
  }
}

// ---------------------------------------------------------------------------
// generic 128-K GEMM via bf16x3 MFMA (final projection, in-place safe)
// ---------------------------------------------------------------------------
__global__ __launch_bounds__(256) void gemm128_mfma_kernel(
    const float* __restrict__ x, const u16* __restrict__ wh,
    const u16* __restrict__ wl, const float* __restrict__ b,
    float* __restrict__ out) {
  __shared__ __align__(16) u16 xsh[16 * GS];
  __shared__ __align__(16) u16 xsl[16 * GS];
  int r0 = blockIdx.x * 64;
  #pragma unroll
  for (int it = 0; it < 8; ++it) {
    int idx4 = it * 256 + threadIdx.x;       // 2048 float4s
    int row = idx4 >> 5, cg = idx4 & 31;
    float4 v = *(const float4*)&x[(size_t)(r0 + row) * 128 + cg * 4];
    ushort4 h4, l4; split4(v, h4, l4);
    int o = (cg >> 1) * GS + row * 8 + (cg & 1) * 4;
    *(ushort4*)&xsh[o] = h4; *(ushort4*)&xsl[o] = l4;
  }
  __syncthreads();
  int wid = threadIdx.x >> 6, lane = threadIdx.x & 63;
  int r = lane & 15, g = lane >> 4;
  f32x4 acc[8] = {};
  #pragma unroll
  for (int kk = 0; kk < 4; ++kk) {
    bf16x8 ah = *(const bf16x8*)&xsh[(kk * 4 + g) * GS + (wid * 16 + r) * 8];
    bf16x8 al = *(const bf16x8*)&xsl[(kk * 4 + g) * GS + (wid * 16 + r) * 8];
    #pragma unroll
    for (int ct = 0; ct < 8; ++ct) {
      int o = ct * 16 + r;
      bf16x8 bh = *(const bf16x8*)&wh[o * 128 + kk * 32 + g * 8];
      bf16x8 bl = *(const bf16x8*)&wl[o * 128 + kk * 32 + g * 8];
      acc[ct] = MFMA(ah, bh, acc[ct]);
      acc[ct] = MFMA(ah, bl, acc[ct]);
      acc[ct] = MFMA(al, bh, acc[ct]);
    }
  }
  #pragma unroll
  for (int ct = 0; ct < 8; ++ct) {
    int col = ct * 16 + r;
    #pragma unroll
    for (int reg = 0; reg < 4; ++reg) {
      int row = r0 + wid * 16 + g * 4 + reg;
      out[(size_t)row * 128 + col] = acc[ct][reg] + b[col];
    }
  }
}

// ---------------------------------------------------------------------------
// conv-as-GEMM, bf16x3 MFMA, pre-split input, LDS-staged weights, pipelined.
// BM=64 tokens, N=64 outs, BK=32, NT=16 K-steps per block. SEG==1 -> direct y.
// ---------------------------------------------------------------------------
template <int P, int NW, int SEG>
__device__ __forceinline__ void conv_body(
    int mblk, int seg, const u16* __restrict__ inph, const u16* __restrict__ inpl,
    const u16* __restrict__ wh, const u16* __restrict__ wl,
    float* __restrict__ dst, const float* __restrict__ bias,
    u16* ash, u16* asl, u16* wsh, u16* wsl) {
  constexpr int K    = 128 * P * P;
  constexpr int KSEG = K / SEG;
  constexpr int NT   = KSEG / 32;
  constexpr int HWIN = H_ / NW;
  constexpr int G    = HWIN / P;
  constexpr int L    = G * G;
  constexpr int M    = 4 * NW * NW * L;
  constexpr int LGL  = (L == 256) ? 8 : 6;
  constexpr int LGG  = (G == 16) ? 4 : 3;
  constexpr int LGNW = (NW == 8) ? 3 : (NW == 4) ? 2 : (NW == 2) ? 1 : 0;
  constexpr int LGP  = (P == 8) ? 3 : (P == 4) ? 2 : 1;
  constexpr int LGP2 = 2 * LGP;
  int tid = threadIdx.x, wid = tid >> 6, lane = tid & 63;
  int r = lane & 15, g = lane >> 4;
  int t0 = mblk * 64;
  int kq = tid & 7;
  int kbase = seg * KSEG;

  // hoisted per-thread gather row decode (2 rows per thread)
  size_t rbase[2];
  #pragma unroll
  for (int hh = 0; hh < 2; ++hh) {
    int row = (tid >> 3) + hh * 32;
    int tglob = t0 + row;
    int bwin = tglob >> LGL;
    int loc  = tglob & (L - 1);
    int n    = bwin >> (2 * LGNW);
    int wrem = bwin & (NW * NW - 1);
    int wy = wrem >> LGNW, wx = wrem & (NW - 1);
    int oh = loc >> LGG,   ow = loc & (G - 1);
    rbase[hh] = (size_t)n * C_ * HW_ + (size_t)(wy * HWIN + oh * P) * W_ +
                wx * HWIN + ow * P;
  }
  int ldso = (kq >> 1) * GS + (tid >> 3) * 8 + (kq & 1) * 4;
  // weight stage mapping: thread -> (out row, 16B chunk)
  int wo = tid >> 2, wpart = tid & 3;
  const u16* wrowh = wh + (size_t)wo * K + kbase + wpart * 8;
  const u16* wrowl = wl + (size_t)wo * K + kbase + wpart * 8;
  int wlo_ = wo * 40 + wpart * 8;

  f32x4 acc[4] = {};
  ushort4 avh[2], avl[2];
  uint4 wvh, wvl;

  auto LOADSTEP = [&](int kt) {
    int k = kbase + kt * 32 + kq * 4;
    int ci = k >> LGP2;
    int wp = k & (P * P - 1);
    if constexpr (P >= 4) {
      int kh = wp >> LGP, kw = wp & (P - 1);
      size_t koff = (size_t)ci * HW_ + kh * W_ + kw;
      #pragma unroll
      for (int hh = 0; hh < 2; ++hh) {
        avh[hh] = *(const ushort4*)&inph[rbase[hh] + koff];
        avl[hh] = *(const ushort4*)&inpl[rbase[hh] + koff];
      }
    } else {
      size_t koff = (size_t)ci * HW_;
      #pragma unroll
      for (int hh = 0; hh < 2; ++hh) {
        union { uint2 u; ushort4 s; } cv;
        cv.u.x = *(const u32*)&inph[rbase[hh] + koff];
        cv.u.y = *(const u32*)&inph[rbase[hh] + koff + W_];
        avh[hh] = cv.s;
        cv.u.x = *(const u32*)&inpl[rbase[hh] + koff];
        cv.u.y = *(const u32*)&inpl[rbase[hh] + koff + W_];
        avl[hh] = cv.s;
      }
    }
    wvh = *(const uint4*)(wrowh + kt * 32);
    wvl = *(const uint4*)(wrowl + kt * 32);
  };

  LOADSTEP(0);
  for (int kt = 0; kt < NT; ++kt) {
    __syncthreads();                    // prior MFMA phase done reading LDS
    *(ushort4*)&ash[ldso]       = avh[0];
    *(ushort4*)&ash[ldso + 256] = avh[1];
    *(ushort4*)&asl[ldso]       = avl[0];
    *(ushort4*)&asl[ldso + 256] = avl[1];
    *(uint4*)&wsh[wlo_] = wvh;
    *(uint4*)&wsl[wlo_] = wvl;
    __syncthreads();
    if (kt + 1 < NT) LOADSTEP(kt + 1);  // prefetch overlaps MFMA phase
    bf16x8 ahf = *(const bf16x8*)&ash[g * GS + (wid * 16 + r) * 8];
    bf16x8 alf = *(const bf16x8*)&asl[g * GS + (wid * 16 + r) * 8];
    #pragma unroll
    for (int ct = 0; ct < 4; ++ct) {
      bf16x8 bh = *(const bf16x8*)&wsh[(ct * 16 + r) * 40 + g * 8];
      bf16x8 bl = *(const bf16x8*)&wsl[(ct * 16 + r) * 40 + g * 8];
      acc[ct] = MFMA(ahf, bh, acc[ct]);
      acc[ct] = MFMA(ahf, bl, acc[ct]);
      acc[ct] = MFMA(alf, bh, acc[ct]);
    }
  }
  #pragma unroll
  for (int ct = 0; ct < 4; ++ct) {
    int o = ct * 16 + r;
    #pragma unroll
    for (int reg = 0; reg < 4; ++reg) {
      int row = t0 + wid * 16 + g * 4 + reg;
      if constexpr (SEG == 1) dst[(size_t)row * 64 + o] = acc[ct][reg] + bias[o];
      else                    dst[((size_t)seg * M + row) * 64 + o] = acc[ct][reg];
    }
  }
}

__global__ __launch_bounds__(256) void conv_mfma_kernel(
    const u16* __restrict__ inph, const u16* __restrict__ inpl,
    const u16* __restrict__ wsh_g, const u16* __restrict__ wsl_g,
    const float* __restrict__ b4, float* __restrict__ part,
    float* __restrict__ y) {
  __shared__ __align__(16) u16 ash[4 * GS];
  __shared__ __align__(16) u16 asl[4 * GS];
  __shared__ __align__(16) u16 wsh[64 * 40];
  __shared__ __align__(16) u16 wsl[64 * 40];
  int bid = blockIdx.x;
  if (bid < 256) {            // head1: 16 mblk x 16 seg
    conv_body<8, 1, 16>(bid & 15, bid >> 4, inph, inpl, wsh_g + OS1, wsl_g + OS1,
                        part, nullptr, ash, asl, wsh, wsl);
  } else if (bid < 512) {     // head2: 64 mblk x 4 seg
    int lb = bid - 256;
    conv_body<4, 2, 4>(lb & 63, lb >> 6, inph, inpl, wsh_g + OS2, wsl_g + OS2,
                       part + 1048576, nullptr, ash, asl, wsh, wsl);
  } else if (bid < 768) {     // head3: 64 mblk x 4 seg
    int lb = bid - 512;
    conv_body<4, 4, 4>(lb & 63, lb >> 6, inph, inpl, wsh_g + OS3, wsl_g + OS3,
                       part + 2097152, nullptr, ash, asl, wsh, wsl);
  } else {                    // head4: 256 mblk, direct
    conv_body<2, 8, 1>(bid - 768, 0, inph, inpl, wsh_g + OS4, wsl_g + OS4,
                       y + (size_t)9216 * 64, b4, ash, asl, wsh, wsl);
  }
}

// reduce K-split partials for heads 1-3
__global__ __launch_bounds__(256) void reduce_kernel(
    const float* __restrict__ part, const float* __restrict__ b1,
    const float* __restrict__ b2, const float* __restrict__ b3,
    float* __restrict__ y) {
  int idx = blockIdx.x * 256 + threadIdx.x;   // grid exactly 589824/256 = 2304
  int tg = idx >> 6, o = idx & 63;
  float s;
  if (tg < 1024) {
    s = b1[o];
    #pragma unroll
    for (int sg = 0; sg < 16; ++sg) s += part[((size_t)sg * 1024 + tg) * 64 + o];
  } else if (tg < 5120) {
    int t = tg - 1024;
    const float* p2 = part + 1048576;
    s = b2[o];
    #pragma unroll
    for (int sg = 0; sg < 4; ++sg) s += p2[((size_t)sg * 4096 + t) * 64 + o];
  } else {
    int t = tg - 5120;
    const float* p3 = part + 2097152;
    s = b3[o];
    #pragma unroll
    for (int sg = 0; sg < 4; ++sg) s += p3[((size_t)sg * 4096 + t) * 64 + o];
  }
  y[(size_t)tg * 64 + o] = s;
}

// ---------------------------------------------------------------------------
// merged per-token LN(64) + exact GELU + KV projection, all heads.
// K written as bf16 [token][32]; V written bf16 window-transposed [d][k].
// ---------------------------------------------------------------------------
struct KvArgs { const float* p[16]; };  // [h*4 + {lnw,lnb,kvw,kvb}]

__global__ __launch_bounds__(256) void lnkv_kernel(
    const float* __restrict__ y, KvArgs a,
    u16* __restrict__ kb, u16* __restrict__ vbT) {
  __shared__ float xg[4][64];
  int wv = threadIdx.x >> 6, lane = threadIdx.x & 63;
  int tg = blockIdx.x * 4 + wv;              // < 25600
  int h = (tg < 1024) ? 0 : (tg < 5120) ? 1 : (tg < 9216) ? 2 : 3;
  const float* lnw = a.p[h * 4 + 0];
  const float* lnb = a.p[h * 4 + 1];
  const float* kvw = a.p[h * 4 + 2];
  const float* kvb = a.p[h * 4 + 3];
  float x = y[(size_t)tg * 64 + lane];
  float s = x;
  for (int m = 1; m < 64; m <<= 1) s += __shfl_xor(s, m, 64);
  float mean = s * (1.0f / 64.0f);
  float d = x - mean;
  float v = d * d;
  for (int m = 1; m < 64; m <<= 1) v += __shfl_xor(v, m, 64);
  v *= (1.0f / 64.0f);
  float xn = d * rsqrtf(v + 1e-5f) * lnw[lane] + lnb[lane];
  float gg = 0.5f * xn * (1.0f + erff(xn * 0.70710678118654752f));
  xg[wv][lane] = gg;
  __syncthreads();
  float acc = kvb[lane];
  const float* wr = kvw + lane * 64;
  #pragma unroll 8
  for (int c = 0; c < 64; ++c) acc += xg[wv][c] * wr[c];
  if (lane < 32) {
    kb[(size_t)tg * 32 + lane] = f2bf_rne(acc);
  } else {
    int dd = lane - 32;
    int lk   = (h < 2) ? 256 : 64;
    int base = (h == 0) ? 0 : (h == 1) ? 1024 : (h == 2) ? 5120 : 9216;
    int kl = (tg - base) & (lk - 1);
    int wstart = tg - kl;
    vbT[(size_t)wstart * 32 + dd * lk + kl] = f2bf_rne(acc);
  }
}

// ---------------------------------------------------------------------------
// MFMA attention: per wave one 16-q tile vs full window key set (exact softmax)
// ---------------------------------------------------------------------------
template <int NW, int LK>
__device__ __forceinline__ void attn_mfma_body(
    int bid, int head, int head_off, const u16* __restrict__ q,
    const u16* __restrict__ kb, const u16* __restrict__ vbT,
    float* __restrict__ cbuf) {
  constexpr int HWIN = H_ / NW;
  constexpr int LQ   = HWIN * HWIN;       // queries per window
  constexpr int BPW  = LQ / 64;           // blocks per window
  constexpr int NCT  = LK / 16;           // S col tiles
  constexpr int NST  = LK / 32;           // PV k steps
  constexpr int PS   = LK + 8;            // P LDS row stride (u16)
  extern __shared__ __align__(16) u16 plds[];
  int wid = threadIdx.x >> 6, lane = threadIdx.x & 63;
  int g = lane >> 4, c = lane & 15;
  int win  = bid / BPW;
  int tIdx = (bid % BPW) * 4 + wid;
  int n = win / (NW * NW);
  int wrem = win % (NW * NW);
  int wy = wrem / NW, wx = wrem % NW;
  int kstart = head_off + win * LK;
  u16* pw_ = plds + wid * 16 * PS;

  // Q A-frag: row = c (q local = tIdx*16+c), contraction d = g*8..+7
  int j = tIdx * 16 + c;
  int ih = j / HWIN, iw = j % HWIN;
  int t = (wy * HWIN + ih) * W_ + wx * HWIN + iw;
  bf16x8 qa = *(const bf16x8*)&q[((size_t)n * HW_ + t) * 128 + head * 32 + g * 8];

  // S = Q K^T  (B-frag: col = key = c, contraction d = g*8..+7)
  f32x4 sacc[NCT];
  #pragma unroll
  for (int ct = 0; ct < NCT; ++ct) {
    sacc[ct] = f32x4{0.f, 0.f, 0.f, 0.f};
    bf16x8 kf = *(const bf16x8*)&kb[(size_t)(kstart + ct * 16 + c) * 32 + g * 8];
    sacc[ct] = MFMA(qa, kf, sacc[ct]);
  }
  #pragma unroll
  for (int ct = 0; ct < NCT; ++ct)
    #pragma unroll
    for (int reg = 0; reg < 4; ++reg) sacc[ct][reg] *= SCALE_;
  // softmax per row (row = g*4+reg; cols spread over ct regs x 16 lanes)
  #pragma unroll
  for (int reg = 0; reg < 4; ++reg) {
    float mx = -1e30f;
    #pragma unroll
    for (int ct = 0; ct < NCT; ++ct) mx = fmaxf(mx, sacc[ct][reg]);
    mx = fmaxf(mx, __shfl_xor(mx, 1, 64));
    mx = fmaxf(mx, __shfl_xor(mx, 2, 64));
    mx = fmaxf(mx, __shfl_xor(mx, 4, 64));
    mx = fmaxf(mx, __shfl_xor(mx, 8, 64));
    float sm = 0.f;
    #pragma unroll
    for (int ct = 0; ct < NCT; ++ct) {
      float e = __expf(sacc[ct][reg] - mx);
      sacc[ct][reg] = e;
      sm += e;
    }
    sm += __shfl_xor(sm, 1, 64);
    sm += __shfl_xor(sm, 2, 64);
    sm += __shfl_xor(sm, 4, 64);
    sm += __shfl_xor(sm, 8, 64);
    float inv = 1.0f / sm;
    #pragma unroll
    for (int ct = 0; ct < NCT; ++ct) sacc[ct][reg] *= inv;
  }
  // P -> bf16 into per-wave LDS [16 q][LK k], padded stride
  #pragma unroll
  for (int ct = 0; ct < NCT; ++ct)
    #pragma unroll
    for (int reg = 0; reg < 4; ++reg)
      pw_[(g * 4 + reg) * PS + ct * 16 + c] = f2bf_rne(sacc[ct][reg]);
  // PV: O[q][d] += P[q][k] V[k][d]; A-frag row=q=c, B-frag col=d=c
  f32x4 oacc[2] = {};
  #pragma unroll
  for (int st = 0; st < NST; ++st) {
    bf16x8 pa = *(const bf16x8*)&pw_[c * PS + st * 32 + g * 8];
    #pragma unroll
    for (int dt = 0; dt < 2; ++dt) {
      bf16x8 vf = *(const bf16x8*)&vbT[(size_t)kstart * 32 +
                                       (dt * 16 + c) * LK + st * 32 + g * 8];
      oacc[dt] = MFMA(pa, vf, oacc[dt]);
    }
  }
  // write O (C layout: col=c -> d, row=g*4+reg -> q local)
  #pragma unroll
  for (int reg = 0; reg < 4; ++reg) {
    int jo = tIdx * 16 + g * 4 + reg;
    int iho = jo / HWIN, iwo = jo % HWIN;
    int to = (wy * HWIN + iho) * W_ + wx * HWIN + iwo;
    float* op = cbuf + ((size_t)n * HW_ + to) * 128 + head * 32;
    op[c]      = oacc[0][reg];
    op[16 + c] = oacc[1][reg];
  }
}

__global__ __launch_bounds__(256) void attn_kernel(
    const u16* __restrict__ q, const u16* __restrict__ kb,
    const u16* __restrict__ vbT, float* __restrict__ cbuf) {
  int bid = blockIdx.x;
  if      (bid < 1024) attn_mfma_body<1, 256>(bid,        0, 0,    q, kb, vbT, cbuf);
  else if (bid < 2048) attn_mfma_body<2, 256>(bid - 1024, 1, 1024, q, kb, vbT, cbuf);
  else if (bid < 3072) attn_mfma_body<4, 64 >(bid - 2048, 2, 5120, q, kb, vbT, cbuf);
  else                 attn_mfma_body<8, 64 >(bid - 3072, 3, 9216, q, kb, vbT, cbuf);
}

// ---------------------------------------------------------------------------
extern "C" void kernel_launch(void* const* d_in, const int* in_sizes, int n_in,
                              void* d_out, int out_size, void* d_ws, size_t ws_size,
                              hipStream_t stream) {
  const float* inp = (const float*)d_in[0];
  const float* nw  = (const float*)d_in[1];
  const float* nb  = (const float*)d_in[2];
  const float* qw  = (const float*)d_in[3];
  const float* qb  = (const float*)d_in[4];
  const float* pw  = (const float*)d_in[29];
  const float* pb  = (const float*)d_in[30];

  float* ws   = (float*)d_ws;
  u16*   qb16 = (u16*)(ws + QB_OFF);
  float* y    = ws + Y_OFF;
  u16*   kb   = (u16*)(ws + KB_OFF);
  u16*   vbT  = (u16*)(ws + VT_OFF);
  float* part = ws + PART_OFF;
  u16*   wsp  = (u16*)(ws + WSP_OFF);
  u16*   whi  = wsp;
  u16*   wlo  = wsp + TOTW;
  u16*   inph = (u16*)(ws + INH_OFF);
  u16*   inpl = (u16*)(ws + INL_OFF);
  float* cbuf = (float*)d_out;

  // 0) split weights + input to bf16 hi/lo
  split_w_kernel<<<TOTW / 256, 256, 0, stream>>>(
      qw, pw, (const float*)d_in[5], (const float*)d_in[11],
      (const float*)d_in[17], (const float*)d_in[23], whi, wlo);
  presplit_kernel<<<8192, 256, 0, stream>>>(inp, inph, inpl);

  // 1) fused LN + Q projection (MFMA) -> bf16 q
  lnq_mfma_kernel<<<1024, 256, 0, stream>>>(inp, nw, nb, whi + OQW, wlo + OQW,
                                            qb, qb16);

  // 2) all 4 patch-embed convs in one launch (MFMA, NT=16 each)
  conv_mfma_kernel<<<1024, 256, 0, stream>>>(inph, inpl, whi, wlo,
                                             (const float*)d_in[24], part, y);

  // 3) reduce K-split partials (heads 1-3)
  reduce_kernel<<<2304, 256, 0, stream>>>(part, (const float*)d_in[6],
                                          (const float*)d_in[12],
                                          (const float*)d_in[18], y);

  // 4) merged LN+GELU+KV projection (bf16 K, window-transposed bf16 V)
  KvArgs ka;
  ka.p[0]  = (const float*)d_in[7];  ka.p[1]  = (const float*)d_in[8];
  ka.p[2]  = (const float*)d_in[9];  ka.p[3]  = (const float*)d_in[10];
  ka.p[4]  = (const float*)d_in[13]; ka.p[5]  = (const float*)d_in[14];
  ka.p[6]  = (const float*)d_in[15]; ka.p[7]  = (const float*)d_in[16];
  ka.p[8]  = (const float*)d_in[19]; ka.p[9]  = (const float*)d_in[20];
  ka.p[10] = (const float*)d_in[21]; ka.p[11] = (const float*)d_in[22];
  ka.p[12] = (const float*)d_in[25]; ka.p[13] = (const float*)d_in[26];
  ka.p[14] = (const float*)d_in[27]; ka.p[15] = (const float*)d_in[28];
  lnkv_kernel<<<6400, 256, 0, stream>>>(y, ka, kb, vbT);

  // 5) MFMA attention (per-wave P tile in LDS: 4 * 16 * 264 * 2 = 33792 B)
  attn_kernel<<<4096, 256, 33792, stream>>>(qb16, kb, vbT, cbuf);

  // 6) final projection, in place on d_out (MFMA)
  gemm128_mfma_kernel<<<1024, 256, 0, stream>>>(cbuf, whi + OPW, wlo + OPW, pb,
                                                (float*)d_out);
}